// Round 1
// baseline (704.283 us; speedup 1.0000x reference)
//
#include <hip/hip_runtime.h>
#include <math.h>

// Problem constants: B=1, S=2048, E=1024, n_head=16, hs=64.
//
// Pipeline:
//   1. qkv  = x @ W_qkv^T + b_qkv          (NT GEMM, 2048x3072x1024)
//   2. qrot = q @ rotary                   (NN GEMM, 2048x1024x1024)
//   3. y    = flash-attention(qrot, k, v)  (16 heads, hs=64)
//   4. out  = y @ W_dense^T + b_dense      (NT GEMM, 2048x1024x1024)
//
// Workspace layout (fp32): qkv[2048*3072] | qrot[2048*1024] | y[2048*1024]
// = 41,943,040 bytes required in d_ws.

#define TILE_M 128
#define TILE_N 128
#define TILE_K 16

// ---------------------------------------------------------------------------
// Tiled fp32 GEMM:  C[M,N] = A[M,K] * op(B) + bias
//   BT=true : B stored [N,K] row-major (op(B)=B^T)  -- torch Linear weight
//   BT=false: B stored [K,N] row-major
// 256 threads, 8x8 micro-tile per thread in a 4+4 split pattern.
// ---------------------------------------------------------------------------
template <bool BT, bool HAS_BIAS>
__global__ __launch_bounds__(256) void gemm_f32(
    const float* __restrict__ A, int lda,
    const float* __restrict__ B, int ldb,
    const float* __restrict__ bias,
    float* __restrict__ C, int ldc,
    int M, int N, int K)
{
    __shared__ float As[TILE_K][TILE_M + 4];
    __shared__ float Bs[TILE_K][TILE_N + 4];

    const int t  = threadIdx.x;
    const int tx = t & 15;       // n dimension
    const int ty = t >> 4;       // m dimension
    const int bm = blockIdx.y * TILE_M;
    const int bn = blockIdx.x * TILE_N;

    // loader indices: 4 threads per row, 4 consecutive floats each
    const int la_r = t >> 2;         // 0..63
    const int la_c = (t & 3) << 2;   // 0,4,8,12
    // NN B loader: 32 threads per k-row
    const int lb_r = t >> 5;         // 0..7
    const int lb_c = (t & 31) << 2;  // 0..124

    float acc[8][8];
#pragma unroll
    for (int i = 0; i < 8; ++i)
#pragma unroll
        for (int j = 0; j < 8; ++j) acc[i][j] = 0.f;

    for (int k0 = 0; k0 < K; k0 += TILE_K) {
        // ---- stage A tile (transposed store: As[k][m]) ----
#pragma unroll
        for (int p = 0; p < 2; ++p) {
            const int row = la_r + p * 64;
            const float4 v = *(const float4*)&A[(size_t)(bm + row) * lda + k0 + la_c];
            As[la_c + 0][row] = v.x;
            As[la_c + 1][row] = v.y;
            As[la_c + 2][row] = v.z;
            As[la_c + 3][row] = v.w;
        }
        // ---- stage B tile ----
        if (BT) {
#pragma unroll
            for (int p = 0; p < 2; ++p) {
                const int row = la_r + p * 64;  // n index
                const float4 v = *(const float4*)&B[(size_t)(bn + row) * ldb + k0 + la_c];
                Bs[la_c + 0][row] = v.x;
                Bs[la_c + 1][row] = v.y;
                Bs[la_c + 2][row] = v.z;
                Bs[la_c + 3][row] = v.w;
            }
        } else {
#pragma unroll
            for (int p = 0; p < 2; ++p) {
                const int kk = lb_r + p * 8;
                *(float4*)&Bs[kk][lb_c] =
                    *(const float4*)&B[(size_t)(k0 + kk) * ldb + bn + lb_c];
            }
        }
        __syncthreads();

        // ---- compute ----
#pragma unroll
        for (int kk = 0; kk < TILE_K; ++kk) {
            float a[8], b[8];
            *(float4*)&a[0] = *(const float4*)&As[kk][ty * 4];
            *(float4*)&a[4] = *(const float4*)&As[kk][64 + ty * 4];
            *(float4*)&b[0] = *(const float4*)&Bs[kk][tx * 4];
            *(float4*)&b[4] = *(const float4*)&Bs[kk][64 + tx * 4];
#pragma unroll
            for (int i = 0; i < 8; ++i)
#pragma unroll
                for (int j = 0; j < 8; ++j)
                    acc[i][j] = fmaf(a[i], b[j], acc[i][j]);
        }
        __syncthreads();
    }

    // ---- epilogue ----
#pragma unroll
    for (int ii = 0; ii < 2; ++ii) {
#pragma unroll
        for (int i = 0; i < 4; ++i) {
            const int row = bm + ii * 64 + ty * 4 + i;
#pragma unroll
            for (int jj = 0; jj < 2; ++jj) {
                const int col = bn + jj * 64 + tx * 4;
                float4 v;
                v.x = acc[ii * 4 + i][jj * 4 + 0];
                v.y = acc[ii * 4 + i][jj * 4 + 1];
                v.z = acc[ii * 4 + i][jj * 4 + 2];
                v.w = acc[ii * 4 + i][jj * 4 + 3];
                if (HAS_BIAS) {
                    v.x += bias[col + 0];
                    v.y += bias[col + 1];
                    v.z += bias[col + 2];
                    v.w += bias[col + 3];
                }
                *(float4*)&C[(size_t)row * ldc + col] = v;
            }
        }
    }
}

// ---------------------------------------------------------------------------
// Flash-style attention, fp32, one (64-row q-tile, head) per block.
// Q, K, P stored TRANSPOSED in LDS (dim-major) so inner loops are
// 2x ds_read_b128 + 16 FMA per k -> VALU-bound, not LDS-bound.
// ---------------------------------------------------------------------------
__global__ __launch_bounds__(256) void attn_f32(
    const float* __restrict__ qrot,  // [2048,1024]
    const float* __restrict__ qkv,   // [2048,3072]
    float* __restrict__ y)           // [2048,1024]
{
    const int E = 1024, LDQKV = 3072, HS = 64;

    __shared__ float Qt[64][68];  // [dim][qrow]
    __shared__ float Kt[64][68];  // [dim][key]
    __shared__ float Vs[64][68];  // [key][dim]
    __shared__ float Pt[64][68];  // [key][qrow]

    const int t  = threadIdx.x;
    const int tx = t & 15;  // key cols (QK) / dim cols (PV)
    const int ty = t >> 4;  // q rows
    const int q0 = blockIdx.x * 64;
    const int h  = blockIdx.y;

    const int lr = t >> 4;         // 0..15 (row within pass)
    const int lc = (t & 15) << 2;  // 0..60 (4-float column group)

    // ---- load Q tile, scaled by 1/sqrt(hs)=1/8, transposed into LDS ----
#pragma unroll
    for (int p = 0; p < 4; ++p) {
        const int row = lr + p * 16;
        const float4 v = *(const float4*)&qrot[(size_t)(q0 + row) * E + h * HS + lc];
        Qt[lc + 0][row] = v.x * 0.125f;
        Qt[lc + 1][row] = v.y * 0.125f;
        Qt[lc + 2][row] = v.z * 0.125f;
        Qt[lc + 3][row] = v.w * 0.125f;
    }

    float m_run[4], l_run[4], o[4][4];
#pragma unroll
    for (int i = 0; i < 4; ++i) {
        m_run[i] = -INFINITY;
        l_run[i] = 0.f;
#pragma unroll
        for (int j = 0; j < 4; ++j) o[i][j] = 0.f;
    }

    for (int kt = 0; kt < 32; ++kt) {
        __syncthreads();  // previous iteration fully consumed K/V/P (also covers Q load)
        const int k0 = kt * 64;
#pragma unroll
        for (int p = 0; p < 4; ++p) {
            const int row = lr + p * 16;
            const size_t base = (size_t)(k0 + row) * LDQKV + h * HS + lc;
            const float4 kv = *(const float4*)&qkv[base + E];       // K slice
            Kt[lc + 0][row] = kv.x;
            Kt[lc + 1][row] = kv.y;
            Kt[lc + 2][row] = kv.z;
            Kt[lc + 3][row] = kv.w;
            const float4 vv = *(const float4*)&qkv[base + 2 * E];   // V slice
            Vs[row][lc + 0] = vv.x;
            Vs[row][lc + 1] = vv.y;
            Vs[row][lc + 2] = vv.z;
            Vs[row][lc + 3] = vv.w;
        }
        __syncthreads();

        // ---- S = (Q/8) K^T : 4x4 per thread ----
        float s[4][4];
#pragma unroll
        for (int i = 0; i < 4; ++i)
#pragma unroll
            for (int j = 0; j < 4; ++j) s[i][j] = 0.f;

        for (int k = 0; k < 64; ++k) {
            float4 qv = *(const float4*)&Qt[k][ty * 4];
            float4 kv = *(const float4*)&Kt[k][tx * 4];
            const float qa[4] = {qv.x, qv.y, qv.z, qv.w};
            const float kb[4] = {kv.x, kv.y, kv.z, kv.w};
#pragma unroll
            for (int i = 0; i < 4; ++i)
#pragma unroll
                for (int j = 0; j < 4; ++j)
                    s[i][j] = fmaf(qa[i], kb[j], s[i][j]);
        }

        // ---- online softmax (rows shared across the 16-lane tx group) ----
#pragma unroll
        for (int i = 0; i < 4; ++i) {
            float mx = fmaxf(fmaxf(s[i][0], s[i][1]), fmaxf(s[i][2], s[i][3]));
#pragma unroll
            for (int off = 1; off < 16; off <<= 1)
                mx = fmaxf(mx, __shfl_xor(mx, off));
            const float m_new = fmaxf(m_run[i], mx);
            const float corr = __expf(m_run[i] - m_new);
            float sum = 0.f;
#pragma unroll
            for (int j = 0; j < 4; ++j) {
                const float p = __expf(s[i][j] - m_new);
                Pt[tx * 4 + j][ty * 4 + i] = p;  // transposed store
                sum += p;
            }
#pragma unroll
            for (int off = 1; off < 16; off <<= 1)
                sum += __shfl_xor(sum, off);
            l_run[i] = l_run[i] * corr + sum;
            m_run[i] = m_new;
#pragma unroll
            for (int j = 0; j < 4; ++j) o[i][j] *= corr;
        }
        __syncthreads();

        // ---- O += P @ V : per k(key): 2x b128 + 16 FMA ----
        for (int k = 0; k < 64; ++k) {
            float4 pv = *(const float4*)&Pt[k][ty * 4];
            float4 vv = *(const float4*)&Vs[k][tx * 4];
            const float pa[4] = {pv.x, pv.y, pv.z, pv.w};
            const float vb[4] = {vv.x, vv.y, vv.z, vv.w};
#pragma unroll
            for (int i = 0; i < 4; ++i)
#pragma unroll
                for (int j = 0; j < 4; ++j)
                    o[i][j] = fmaf(pa[i], vb[j], o[i][j]);
        }
    }

    // ---- epilogue: normalize and write y[s][h*64+d] ----
#pragma unroll
    for (int i = 0; i < 4; ++i) {
        const float inv = 1.f / l_run[i];
        float4 v;
        v.x = o[i][0] * inv;
        v.y = o[i][1] * inv;
        v.z = o[i][2] * inv;
        v.w = o[i][3] * inv;
        *(float4*)&y[(size_t)(q0 + ty * 4 + i) * E + h * HS + tx * 4] = v;
    }
}

// ---------------------------------------------------------------------------
extern "C" void kernel_launch(void* const* d_in, const int* in_sizes, int n_in,
                              void* d_out, int out_size, void* d_ws, size_t ws_size,
                              hipStream_t stream)
{
    const float* x       = (const float*)d_in[0];  // [2048,1024]
    const float* W_qkv   = (const float*)d_in[1];  // [3072,1024]
    const float* b_qkv   = (const float*)d_in[2];  // [3072]
    const float* rotary  = (const float*)d_in[3];  // [1024,1024]
    const float* W_dense = (const float*)d_in[4];  // [1024,1024]
    const float* b_dense = (const float*)d_in[5];  // [1024]
    float* out = (float*)d_out;                    // [2048,1024]

    float* ws   = (float*)d_ws;
    float* qkv  = ws;                                  // 2048*3072
    float* qrot = qkv + (size_t)2048 * 3072;           // 2048*1024
    float* y    = qrot + (size_t)2048 * 1024;          // 2048*1024
    // requires ws_size >= 41,943,040 bytes

    const dim3 blk(256);

    // 1) qkv = x @ W_qkv^T + b_qkv
    gemm_f32<true, true><<<dim3(3072 / TILE_N, 2048 / TILE_M), blk, 0, stream>>>(
        x, 1024, W_qkv, 1024, b_qkv, qkv, 3072, 2048, 3072, 1024);

    // 2) qrot = q @ rotary   (q = first E columns of qkv, lda=3072)
    gemm_f32<false, false><<<dim3(1024 / TILE_N, 2048 / TILE_M), blk, 0, stream>>>(
        qkv, 3072, rotary, 1024, nullptr, qrot, 1024, 2048, 1024, 1024);

    // 3) attention
    attn_f32<<<dim3(32, 16), blk, 0, stream>>>(qrot, qkv, y);

    // 4) out = y @ W_dense^T + b_dense
    gemm_f32<true, true><<<dim3(1024 / TILE_N, 2048 / TILE_M), blk, 0, stream>>>(
        y, 1024, W_dense, 1024, b_dense, out, 1024, 2048, 1024, 1024);
}

// Round 2
// 361.838 us; speedup vs baseline: 1.9464x; 1.9464x over previous
//
#include <hip/hip_runtime.h>
#include <math.h>

// B=1, S=2048, E=1024, nh=16, hs=64.
// Pipeline (all GEMMs bf16-MFMA, fp32 accumulate):
//   casts: x,W_qkv,W_dense -> bf16; rotary -> bf16 transposed [N,K]
//   1. qkv_bf  = x @ W_qkv^T + b_qkv      (NT, 2048x3072x1024) -> bf16
//   2. qrot_bf = q @ rot_t^T              (NT, 2048x1024x1024) -> bf16
//   3. y_bf    = flashattn(qrot,K,V)      (fp32 VALU compute, bf16 I/O)
//   4. out     = y @ W_dense^T + b_dense  (NT, 2048x1024x1024) -> fp32
//
// Workspace (35,651,584 B):
//   qkv_bf[2048*3072] qrot_bf[2048*1024] y_bf[2048*1024]
//   x_bf[2048*1024]   wq_bf[3072*1024]   rot_t[1024*1024] wd_bf[1024*1024]

typedef float  f32x4  __attribute__((ext_vector_type(4)));
typedef __bf16 bf16x8 __attribute__((ext_vector_type(8)));

__device__ __forceinline__ unsigned short f2bf(float f) {
    unsigned int u = __builtin_bit_cast(unsigned int, f);
    u += 0x7FFFu + ((u >> 16) & 1u);            // RNE
    return (unsigned short)(u >> 16);
}
__device__ __forceinline__ float bf2f(unsigned short h) {
    return __builtin_bit_cast(float, (unsigned int)h << 16);
}
__device__ __forceinline__ void glds16(const unsigned short* g, unsigned short* l) {
    __builtin_amdgcn_global_load_lds(
        (const __attribute__((address_space(1))) void*)g,
        (__attribute__((address_space(3))) void*)l, 16, 0, 0);
}
__device__ __forceinline__ bf16x8 ldfrag(const unsigned short* p) {
    return __builtin_bit_cast(bf16x8, *(const int4*)p);
}

// ---------------------------------------------------------------------------
// bf16 MFMA GEMM, NT: C[M,N] = A[M,K] * B[N,K]^T (+bias), m97 structure.
// 256 thr = 4 waves in WGM x WGN grid; per wave FM x FN 16x16 frags; BK=32.
// ---------------------------------------------------------------------------
template <int BM, int BN, int WGM, int WGN, bool OUT_BF16, bool HAS_BIAS>
__global__ __launch_bounds__(256) void gemm_bf16mfma(
    const unsigned short* __restrict__ A, int lda,
    const unsigned short* __restrict__ B, int ldb,
    const float* __restrict__ bias,
    void* __restrict__ Cv, int ldc, int K)
{
    constexpr int WM = BM / WGM, WN = BN / WGN;
    constexpr int FM = WM / 16, FN = WN / 16;
    __shared__ unsigned short As[BM * 32];
    __shared__ unsigned short Bs[BN * 32];

    const int t    = threadIdx.x;
    const int lane = t & 63;
    const int wid  = t >> 6;
    const int wr   = wid / WGN;
    const int wc   = wid % WGN;
    const int bm   = blockIdx.y * BM;
    const int bn   = blockIdx.x * BN;

    // staging: thread t loads 16B (8 bf16): row t>>2, k-chunk (t&3)*8
    const int srow = t >> 2;
    const int scol = (t & 3) * 8;
    unsigned short* ldsA = As + (t & 192) * 8;  // wave-uniform base, +lane*16B by HW
    unsigned short* ldsB = Bs + (t & 192) * 8;

    const int fr = lane & 15;   // frag row (A: m, B: n), C/D col
    const int fq = lane >> 4;   // k-block / C/D row-quad

    f32x4 acc[FM][FN];
#pragma unroll
    for (int i = 0; i < FM; ++i)
#pragma unroll
        for (int j = 0; j < FN; ++j) acc[i][j] = (f32x4){0.f, 0.f, 0.f, 0.f};

    const size_t a_base = (size_t)(bm + srow) * lda + scol;
    const size_t b_base = (size_t)(bn + srow) * ldb + scol;

    for (int k0 = 0; k0 < K; k0 += 32) {
#pragma unroll
        for (int p = 0; p < BM / 64; ++p)
            glds16(A + a_base + (size_t)p * 64 * lda + k0, ldsA + p * 2048);
#pragma unroll
        for (int p = 0; p < BN / 64; ++p)
            glds16(B + b_base + (size_t)p * 64 * ldb + k0, ldsB + p * 2048);
        __syncthreads();   // compiler drains vmcnt before barrier

        bf16x8 aF[FM], bF[FN];
#pragma unroll
        for (int m = 0; m < FM; ++m)
            aF[m] = ldfrag(As + (wr * WM + m * 16 + fr) * 32 + fq * 8);
#pragma unroll
        for (int n = 0; n < FN; ++n)
            bF[n] = ldfrag(Bs + (wc * WN + n * 16 + fr) * 32 + fq * 8);
#pragma unroll
        for (int m = 0; m < FM; ++m)
#pragma unroll
            for (int n = 0; n < FN; ++n)
                acc[m][n] = __builtin_amdgcn_mfma_f32_16x16x32_bf16(
                    aF[m], bF[n], acc[m][n], 0, 0, 0);
        __syncthreads();
    }

    // C/D layout (verified m89/m91): col = lane&15, row = (lane>>4)*4 + reg
#pragma unroll
    for (int m = 0; m < FM; ++m) {
        const int row0 = bm + wr * WM + m * 16 + fq * 4;
#pragma unroll
        for (int n = 0; n < FN; ++n) {
            const int col = bn + wc * WN + n * 16 + fr;
            const float bv = HAS_BIAS ? bias[col] : 0.f;
#pragma unroll
            for (int j = 0; j < 4; ++j) {
                const float v = acc[m][n][j] + bv;
                if (OUT_BF16)
                    ((unsigned short*)Cv)[(size_t)(row0 + j) * ldc + col] = f2bf(v);
                else
                    ((float*)Cv)[(size_t)(row0 + j) * ldc + col] = v;
            }
        }
    }
}

// ---------------------------------------------------------------------------
// fp32 -> bf16 cast, 4 elems/thread
// ---------------------------------------------------------------------------
__global__ __launch_bounds__(256) void cast_f32_bf16(
    const float* __restrict__ in, unsigned short* __restrict__ out, int n4)
{
    const int i = blockIdx.x * 256 + threadIdx.x;
    if (i < n4) {
        const float4 v = ((const float4*)in)[i];
        ushort4 o;
        o.x = f2bf(v.x); o.y = f2bf(v.y); o.z = f2bf(v.z); o.w = f2bf(v.w);
        ((ushort4*)out)[i] = o;
    }
}

// ---------------------------------------------------------------------------
// rotary [K=1024][N=1024] fp32 -> rot_t [N][K] bf16 (64x64 LDS tiles)
// ---------------------------------------------------------------------------
__global__ __launch_bounds__(256) void cast_transpose_bf16(
    const float* __restrict__ in, unsigned short* __restrict__ out)
{
    __shared__ unsigned short tile[64][68];
    const int bn = blockIdx.x * 64;  // col of in  (= row of out)
    const int bk = blockIdx.y * 64;  // row of in  (= col of out)
    const int tr = threadIdx.x >> 4;        // 0..15
    const int tc = (threadIdx.x & 15) * 4;  // 0..60

#pragma unroll
    for (int p = 0; p < 4; ++p) {
        const int r = tr + p * 16;
        const float4 v = *(const float4*)&in[(size_t)(bk + r) * 1024 + bn + tc];
        tile[tc + 0][r] = f2bf(v.x);
        tile[tc + 1][r] = f2bf(v.y);
        tile[tc + 2][r] = f2bf(v.z);
        tile[tc + 3][r] = f2bf(v.w);
    }
    __syncthreads();
#pragma unroll
    for (int p = 0; p < 4; ++p) {
        const int r = tr + p * 16;  // n-local
        ushort4 o;
        o.x = tile[r][tc + 0];
        o.y = tile[r][tc + 1];
        o.z = tile[r][tc + 2];
        o.w = tile[r][tc + 3];
        *(ushort4*)&out[(size_t)(bn + r) * 1024 + bk + tc] = o;
    }
}

// ---------------------------------------------------------------------------
// Flash attention, fp32 VALU compute, bf16 I/O. One (64-q-tile, head)/block.
// ---------------------------------------------------------------------------
__global__ __launch_bounds__(256) void attn_bf16(
    const unsigned short* __restrict__ qrot,  // [2048,1024] bf16
    const unsigned short* __restrict__ qkv,   // [2048,3072] bf16
    unsigned short* __restrict__ y)           // [2048,1024] bf16
{
    const int E = 1024, LDQKV = 3072, HS = 64;

    __shared__ float Qt[64][68];
    __shared__ float Kt[64][68];
    __shared__ float Vs[64][68];
    __shared__ float Pt[64][68];

    const int t  = threadIdx.x;
    const int tx = t & 15;
    const int ty = t >> 4;
    const int q0 = blockIdx.x * 64;
    const int h  = blockIdx.y;

    const int lr = t >> 3;        // 0..31
    const int lc = (t & 7) * 8;   // 0..56

    union U8 { int4 v; unsigned short u[8]; };

    // Q tile (scaled 1/8), transposed into LDS
#pragma unroll
    for (int p = 0; p < 2; ++p) {
        const int row = lr + p * 32;
        U8 q; q.v = *(const int4*)&qrot[(size_t)(q0 + row) * E + h * HS + lc];
#pragma unroll
        for (int j = 0; j < 8; ++j) Qt[lc + j][row] = bf2f(q.u[j]) * 0.125f;
    }

    float m_run[4], l_run[4], o[4][4];
#pragma unroll
    for (int i = 0; i < 4; ++i) {
        m_run[i] = -INFINITY;
        l_run[i] = 0.f;
#pragma unroll
        for (int j = 0; j < 4; ++j) o[i][j] = 0.f;
    }

    for (int kt = 0; kt < 32; ++kt) {
        __syncthreads();
        const int k0 = kt * 64;
#pragma unroll
        for (int p = 0; p < 2; ++p) {
            const int row = lr + p * 32;
            const size_t base = (size_t)(k0 + row) * LDQKV + h * HS + lc;
            U8 kv; kv.v = *(const int4*)&qkv[base + E];
#pragma unroll
            for (int j = 0; j < 8; ++j) Kt[lc + j][row] = bf2f(kv.u[j]);
            U8 vv; vv.v = *(const int4*)&qkv[base + 2 * E];
#pragma unroll
            for (int j = 0; j < 8; ++j) Vs[row][lc + j] = bf2f(vv.u[j]);
        }
        __syncthreads();

        // S = (Q/8) K^T, 4x4 per thread
        float s[4][4];
#pragma unroll
        for (int i = 0; i < 4; ++i)
#pragma unroll
            for (int j = 0; j < 4; ++j) s[i][j] = 0.f;

        for (int k = 0; k < 64; ++k) {
            const float4 qv = *(const float4*)&Qt[k][ty * 4];
            const float4 kv = *(const float4*)&Kt[k][tx * 4];
            const float qa[4] = {qv.x, qv.y, qv.z, qv.w};
            const float kb[4] = {kv.x, kv.y, kv.z, kv.w};
#pragma unroll
            for (int i = 0; i < 4; ++i)
#pragma unroll
                for (int j = 0; j < 4; ++j)
                    s[i][j] = fmaf(qa[i], kb[j], s[i][j]);
        }

        // online softmax across the 16-lane tx group
#pragma unroll
        for (int i = 0; i < 4; ++i) {
            float mx = fmaxf(fmaxf(s[i][0], s[i][1]), fmaxf(s[i][2], s[i][3]));
#pragma unroll
            for (int off = 1; off < 16; off <<= 1)
                mx = fmaxf(mx, __shfl_xor(mx, off));
            const float m_new = fmaxf(m_run[i], mx);
            const float corr = __expf(m_run[i] - m_new);
            float sum = 0.f;
#pragma unroll
            for (int j = 0; j < 4; ++j) {
                const float p = __expf(s[i][j] - m_new);
                Pt[tx * 4 + j][ty * 4 + i] = p;
                sum += p;
            }
#pragma unroll
            for (int off = 1; off < 16; off <<= 1)
                sum += __shfl_xor(sum, off);
            l_run[i] = l_run[i] * corr + sum;
            m_run[i] = m_new;
#pragma unroll
            for (int j = 0; j < 4; ++j) o[i][j] *= corr;
        }
        __syncthreads();

        // O += P @ V
        for (int k = 0; k < 64; ++k) {
            const float4 pv = *(const float4*)&Pt[k][ty * 4];
            const float4 vv = *(const float4*)&Vs[k][tx * 4];
            const float pa[4] = {pv.x, pv.y, pv.z, pv.w};
            const float vb[4] = {vv.x, vv.y, vv.z, vv.w};
#pragma unroll
            for (int i = 0; i < 4; ++i)
#pragma unroll
                for (int j = 0; j < 4; ++j)
                    o[i][j] = fmaf(pa[i], vb[j], o[i][j]);
        }
    }

#pragma unroll
    for (int i = 0; i < 4; ++i) {
        const float inv = 1.f / l_run[i];
        ushort4 o4;
        o4.x = f2bf(o[i][0] * inv);
        o4.y = f2bf(o[i][1] * inv);
        o4.z = f2bf(o[i][2] * inv);
        o4.w = f2bf(o[i][3] * inv);
        *(ushort4*)&y[(size_t)(q0 + ty * 4 + i) * E + h * HS + tx * 4] = o4;
    }
}

// ---------------------------------------------------------------------------
extern "C" void kernel_launch(void* const* d_in, const int* in_sizes, int n_in,
                              void* d_out, int out_size, void* d_ws, size_t ws_size,
                              hipStream_t stream)
{
    const float* x       = (const float*)d_in[0];
    const float* W_qkv   = (const float*)d_in[1];
    const float* b_qkv   = (const float*)d_in[2];
    const float* rotary  = (const float*)d_in[3];
    const float* W_dense = (const float*)d_in[4];
    const float* b_dense = (const float*)d_in[5];
    float* out = (float*)d_out;

    char* w = (char*)d_ws;
    unsigned short* qkv_bf  = (unsigned short*)(w);              // 12,582,912 B
    unsigned short* qrot_bf = (unsigned short*)(w + 12582912);   //  4,194,304
    unsigned short* y_bf    = (unsigned short*)(w + 16777216);   //  4,194,304
    unsigned short* x_bf    = (unsigned short*)(w + 20971520);   //  4,194,304
    unsigned short* wq_bf   = (unsigned short*)(w + 25165824);   //  6,291,456
    unsigned short* rot_t   = (unsigned short*)(w + 31457280);   //  2,097,152
    unsigned short* wd_bf   = (unsigned short*)(w + 33554432);   //  2,097,152

    // casts
    cast_f32_bf16<<<2048, 256, 0, stream>>>(x, x_bf, 2048 * 1024 / 4);
    cast_f32_bf16<<<3072, 256, 0, stream>>>(W_qkv, wq_bf, 3072 * 1024 / 4);
    cast_f32_bf16<<<1024, 256, 0, stream>>>(W_dense, wd_bf, 1024 * 1024 / 4);
    cast_transpose_bf16<<<dim3(16, 16), 256, 0, stream>>>(rotary, rot_t);

    // 1) qkv = x @ W_qkv^T + b_qkv  -> bf16
    gemm_bf16mfma<128, 128, 2, 2, true, true><<<dim3(24, 16), 256, 0, stream>>>(
        x_bf, 1024, wq_bf, 1024, b_qkv, qkv_bf, 3072, 1024);

    // 2) qrot = q @ rot_t^T -> bf16   (q = first 1024 cols of qkv_bf, lda=3072)
    gemm_bf16mfma<128, 64, 4, 1, true, false><<<dim3(16, 16), 256, 0, stream>>>(
        qkv_bf, 3072, rot_t, 1024, nullptr, qrot_bf, 1024, 1024);

    // 3) attention
    attn_bf16<<<dim3(32, 16), 256, 0, stream>>>(qrot_bf, qkv_bf, y_bf);

    // 4) out = y @ W_dense^T + b_dense -> fp32
    gemm_bf16mfma<128, 64, 4, 1, false, true><<<dim3(16, 16), 256, 0, stream>>>(
        y_bf, 1024, wd_bf, 1024, b_dense, out, 1024, 1024);
}

// Round 3
// 137.955 us; speedup vs baseline: 5.1052x; 2.6229x over previous
//
#include <hip/hip_runtime.h>
#include <math.h>

// B=1, S=2048, E=1024, nh=16, hs=64.
// Pipeline:
//   casts: x,W_qkv,W_dense -> bf16; rotary -> bf16 transposed [N,K]
//   1. qkv_bf  = x @ W_qkv^T + b_qkv      (NT MFMA, 2048x3072x1024) -> bf16
//   2. vt      = transpose(V part of qkv) -> [1024][2048] bf16
//   3. qrot_bf = q @ rot_t^T              (NT MFMA, 2048x1024x1024) -> bf16
//   4. y_bf    = MFMA flash attention
//   5. out     = y @ W_dense^T + b_dense  (NT MFMA) -> fp32

typedef float  f32x4  __attribute__((ext_vector_type(4)));
typedef __bf16 bf16x8 __attribute__((ext_vector_type(8)));

__device__ __forceinline__ unsigned short f2bf(float f) {
    unsigned int u = __builtin_bit_cast(unsigned int, f);
    u += 0x7FFFu + ((u >> 16) & 1u);            // RNE
    return (unsigned short)(u >> 16);
}
__device__ __forceinline__ float bf2f(unsigned short h) {
    return __builtin_bit_cast(float, (unsigned int)h << 16);
}
__device__ __forceinline__ void glds16(const unsigned short* g, unsigned short* l) {
    __builtin_amdgcn_global_load_lds(
        (const __attribute__((address_space(1))) void*)g,
        (__attribute__((address_space(3))) void*)l, 16, 0, 0);
}
__device__ __forceinline__ bf16x8 ldfrag(const unsigned short* p) {
    return __builtin_bit_cast(bf16x8, *(const int4*)p);
}

// ---------------------------------------------------------------------------
// bf16 MFMA GEMM, NT: C[M,N] = A[M,K] * B[N,K]^T (+bias). (verified r2)
// ---------------------------------------------------------------------------
template <int BM, int BN, int WGM, int WGN, bool OUT_BF16, bool HAS_BIAS>
__global__ __launch_bounds__(256) void gemm_bf16mfma(
    const unsigned short* __restrict__ A, int lda,
    const unsigned short* __restrict__ B, int ldb,
    const float* __restrict__ bias,
    void* __restrict__ Cv, int ldc, int K)
{
    constexpr int WM = BM / WGM, WN = BN / WGN;
    constexpr int FM = WM / 16, FN = WN / 16;
    __shared__ unsigned short As[BM * 32];
    __shared__ unsigned short Bs[BN * 32];

    const int t    = threadIdx.x;
    const int lane = t & 63;
    const int wid  = t >> 6;
    const int wr   = wid / WGN;
    const int wc   = wid % WGN;
    const int bm   = blockIdx.y * BM;
    const int bn   = blockIdx.x * BN;

    const int srow = t >> 2;
    const int scol = (t & 3) * 8;
    unsigned short* ldsA = As + (t & 192) * 8;
    unsigned short* ldsB = Bs + (t & 192) * 8;

    const int fr = lane & 15;
    const int fq = lane >> 4;

    f32x4 acc[FM][FN];
#pragma unroll
    for (int i = 0; i < FM; ++i)
#pragma unroll
        for (int j = 0; j < FN; ++j) acc[i][j] = (f32x4){0.f, 0.f, 0.f, 0.f};

    const size_t a_base = (size_t)(bm + srow) * lda + scol;
    const size_t b_base = (size_t)(bn + srow) * ldb + scol;

    for (int k0 = 0; k0 < K; k0 += 32) {
#pragma unroll
        for (int p = 0; p < BM / 64; ++p)
            glds16(A + a_base + (size_t)p * 64 * lda + k0, ldsA + p * 2048);
#pragma unroll
        for (int p = 0; p < BN / 64; ++p)
            glds16(B + b_base + (size_t)p * 64 * ldb + k0, ldsB + p * 2048);
        __syncthreads();

        bf16x8 aF[FM], bF[FN];
#pragma unroll
        for (int m = 0; m < FM; ++m)
            aF[m] = ldfrag(As + (wr * WM + m * 16 + fr) * 32 + fq * 8);
#pragma unroll
        for (int n = 0; n < FN; ++n)
            bF[n] = ldfrag(Bs + (wc * WN + n * 16 + fr) * 32 + fq * 8);
#pragma unroll
        for (int m = 0; m < FM; ++m)
#pragma unroll
            for (int n = 0; n < FN; ++n)
                acc[m][n] = __builtin_amdgcn_mfma_f32_16x16x32_bf16(
                    aF[m], bF[n], acc[m][n], 0, 0, 0);
        __syncthreads();
    }

#pragma unroll
    for (int m = 0; m < FM; ++m) {
        const int row0 = bm + wr * WM + m * 16 + fq * 4;
#pragma unroll
        for (int n = 0; n < FN; ++n) {
            const int col = bn + wc * WN + n * 16 + fr;
            const float bv = HAS_BIAS ? bias[col] : 0.f;
#pragma unroll
            for (int j = 0; j < 4; ++j) {
                const float v = acc[m][n][j] + bv;
                if (OUT_BF16)
                    ((unsigned short*)Cv)[(size_t)(row0 + j) * ldc + col] = f2bf(v);
                else
                    ((float*)Cv)[(size_t)(row0 + j) * ldc + col] = v;
            }
        }
    }
}

// ---------------------------------------------------------------------------
__global__ __launch_bounds__(256) void cast_f32_bf16(
    const float* __restrict__ in, unsigned short* __restrict__ out, int n4)
{
    const int i = blockIdx.x * 256 + threadIdx.x;
    if (i < n4) {
        const float4 v = ((const float4*)in)[i];
        ushort4 o;
        o.x = f2bf(v.x); o.y = f2bf(v.y); o.z = f2bf(v.z); o.w = f2bf(v.w);
        ((ushort4*)out)[i] = o;
    }
}

// rotary [K][N] fp32 -> rot_t [N][K] bf16
__global__ __launch_bounds__(256) void cast_transpose_bf16(
    const float* __restrict__ in, unsigned short* __restrict__ out)
{
    __shared__ unsigned short tile[64][68];
    const int bn = blockIdx.x * 64;
    const int bk = blockIdx.y * 64;
    const int tr = threadIdx.x >> 4;
    const int tc = (threadIdx.x & 15) * 4;

#pragma unroll
    for (int p = 0; p < 4; ++p) {
        const int r = tr + p * 16;
        const float4 v = *(const float4*)&in[(size_t)(bk + r) * 1024 + bn + tc];
        tile[tc + 0][r] = f2bf(v.x);
        tile[tc + 1][r] = f2bf(v.y);
        tile[tc + 2][r] = f2bf(v.z);
        tile[tc + 3][r] = f2bf(v.w);
    }
    __syncthreads();
#pragma unroll
    for (int p = 0; p < 4; ++p) {
        const int r = tr + p * 16;
        ushort4 o;
        o.x = tile[r][tc + 0];
        o.y = tile[r][tc + 1];
        o.z = tile[r][tc + 2];
        o.w = tile[r][tc + 3];
        *(ushort4*)&out[(size_t)(bn + r) * 1024 + bk + tc] = o;
    }
}

// ---------------------------------------------------------------------------
// V part of qkv [2048 seq][3072] (cols 2048..3071) -> vt [1024][2048]
// ---------------------------------------------------------------------------
__global__ __launch_bounds__(256) void transpose_v(
    const unsigned short* __restrict__ qkv, unsigned short* __restrict__ vt)
{
    __shared__ unsigned short tile[64][65];
    const int bs = blockIdx.x * 64;   // seq
    const int bc = blockIdx.y * 64;   // col
    const int t  = threadIdx.x;

    union U8 { int4 v; unsigned short u[8]; };
#pragma unroll
    for (int p = 0; p < 2; ++p) {
        const int s = (t >> 3) + p * 32;
        const int c = (t & 7) * 8;
        U8 ld;
        ld.v = *(const int4*)&qkv[(size_t)(bs + s) * 3072 + 2048 + bc + c];
#pragma unroll
        for (int i = 0; i < 8; ++i) tile[s][c + i] = ld.u[i];
    }
    __syncthreads();
#pragma unroll
    for (int p = 0; p < 2; ++p) {
        const int r  = (t >> 3) + p * 32;   // col-local
        const int sc = (t & 7) * 8;         // seq-local
        U8 st;
#pragma unroll
        for (int i = 0; i < 8; ++i) st.u[i] = tile[sc + i][r];
        *(int4*)&vt[(size_t)(bc + r) * 2048 + bs + sc] = st.v;
    }
}

// ---------------------------------------------------------------------------
// MFMA flash attention. 4 waves x 16 q-rows, KVBLK=64, D=64.
// Swapped QK^T (A=K,B=Q) -> lane-local q-rows; P b64-packed to LDS;
// PV with A=P, B=Vt. K/Vt glds-staged w/ pre-swizzled src, XOR-swizzled LDS.
// ---------------------------------------------------------------------------
__global__ __launch_bounds__(256) void attn_mfma(
    const unsigned short* __restrict__ qrot,  // [2048][1024]
    const unsigned short* __restrict__ qkv,   // [2048][3072]
    const unsigned short* __restrict__ vt,    // [1024][2048]
    unsigned short* __restrict__ y)           // [2048][1024]
{
    __shared__ unsigned short Klds[2][4096];  // [key][d] swizzled, 8KB each
    __shared__ unsigned short Vlds[2][4096];  // [d][key] swizzled
    __shared__ unsigned short Plds[4][1024];  // per-wave [q][key] swizzled

    const int t    = threadIdx.x;
    const int lane = t & 63;
    const int wid  = t >> 6;
    const int fr   = lane & 15;
    const int fq   = lane >> 4;
    const int q0   = blockIdx.x * 64;
    const int h    = blockIdx.y;

    // staging map: thread covers LDS bytes o = t*16 (+s*4096):
    // row = o>>7, chunk byte = (o&127) ^ ((row&7)<<4)
    const int srow = t >> 3;                        // 0..31
    const int soff = 8 * ((t & 7) ^ (srow & 7));    // elem offset in row
    unsigned short* const kdst = (unsigned short*)Klds[0] + wid * 512;
    unsigned short* const vdst = (unsigned short*)Vlds[0] + wid * 512;

    // fragment-read swizzle (rows are 64 elems = 128B)
    const int fr7_16 = (fr & 7) << 4;
    const int rb0 = ((fq * 16) ^ fr7_16) >> 1;        // kc=0, ushort units
    const int rb1 = ((64 + fq * 16) ^ fr7_16) >> 1;   // kc=1

    // Q fragments (B-operand: lane holds q-row fr, d = kc*32 + fq*8)
    bf16x8 qF[2];
#pragma unroll
    for (int kc = 0; kc < 2; ++kc)
        qF[kc] = ldfrag(&qrot[(size_t)(q0 + wid * 16 + fr) * 1024 + h * 64 + kc * 32 + fq * 8]);

    float mrun = -1e30f, lrun = 0.f;
    f32x4 oacc[4];
#pragma unroll
    for (int n = 0; n < 4; ++n) oacc[n] = (f32x4){0.f, 0.f, 0.f, 0.f};

    // prologue: stage tile 0 into buf 0
#pragma unroll
    for (int s2 = 0; s2 < 2; ++s2) {
        glds16(qkv + (size_t)(srow + 32 * s2) * 3072 + 1024 + h * 64 + soff,
               kdst + s2 * 2048);
        glds16(vt + (size_t)(h * 64 + srow + 32 * s2) * 2048 + soff,
               vdst + s2 * 2048);
    }
    __syncthreads();

    for (int kt = 0; kt < 32; ++kt) {
        const int cb = kt & 1;
        // stage next tile into other buffer (latency hidden under compute)
        if (kt < 31) {
            const int k0n = (kt + 1) * 64;
            const int nbo = (cb ^ 1) * 4096;  // ushort offset of other buffer
#pragma unroll
            for (int s2 = 0; s2 < 2; ++s2) {
                glds16(qkv + (size_t)(k0n + srow + 32 * s2) * 3072 + 1024 + h * 64 + soff,
                       kdst + nbo + s2 * 2048);
                glds16(vt + (size_t)(h * 64 + srow + 32 * s2) * 2048 + k0n + soff,
                       vdst + nbo + s2 * 2048);
            }
        }

        // ---- S^T = K @ Q^T : S[key=m*16+fq*4+j][q=fr] ----
        f32x4 sacc[4];
#pragma unroll
        for (int m = 0; m < 4; ++m) {
            const bf16x8 a0 = ldfrag(&Klds[cb][(m * 16 + fr) * 64 + rb0]);
            const bf16x8 a1 = ldfrag(&Klds[cb][(m * 16 + fr) * 64 + rb1]);
            sacc[m] = __builtin_amdgcn_mfma_f32_16x16x32_bf16(a0, qF[0],
                          (f32x4){0.f, 0.f, 0.f, 0.f}, 0, 0, 0);
            sacc[m] = __builtin_amdgcn_mfma_f32_16x16x32_bf16(a1, qF[1],
                          sacc[m], 0, 0, 0);
        }

        // ---- online softmax (per lane: q-row fr, 16 keys) ----
        float sv[4][4];
        float mx = -1e30f;
#pragma unroll
        for (int m = 0; m < 4; ++m)
#pragma unroll
            for (int j = 0; j < 4; ++j) {
                sv[m][j] = sacc[m][j] * 0.125f;
                mx = fmaxf(mx, sv[m][j]);
            }
        mx = fmaxf(mx, __shfl_xor(mx, 16));
        mx = fmaxf(mx, __shfl_xor(mx, 32));
        const float mnew = fmaxf(mrun, mx);
        const float corr = __expf(mrun - mnew);
        mrun = mnew;

        float ps = 0.f;
#pragma unroll
        for (int m = 0; m < 4; ++m) {
            ushort4 pk;
            float p0 = __expf(sv[m][0] - mnew); ps += p0; pk.x = f2bf(p0);
            float p1 = __expf(sv[m][1] - mnew); ps += p1; pk.y = f2bf(p1);
            float p2 = __expf(sv[m][2] - mnew); ps += p2; pk.z = f2bf(p2);
            float p3 = __expf(sv[m][3] - mnew); ps += p3; pk.w = f2bf(p3);
            // P[q=fr][key = m*16 + fq*4 .. +3], swizzled, 8B store
            *(ushort4*)&Plds[wid][fr * 64 + (((m * 32 + fq * 8) ^ fr7_16) >> 1)] = pk;
        }
        ps += __shfl_xor(ps, 16);
        ps += __shfl_xor(ps, 32);
        lrun = lrun * corr + ps;

        // rescale O (corr for q-row fq*4+j lives in lane 16*fq + fq*4+j)
        const float c0 = __shfl(corr, 20 * fq + 0);
        const float c1 = __shfl(corr, 20 * fq + 1);
        const float c2 = __shfl(corr, 20 * fq + 2);
        const float c3 = __shfl(corr, 20 * fq + 3);
#pragma unroll
        for (int n = 0; n < 4; ++n) {
            oacc[n][0] *= c0; oacc[n][1] *= c1;
            oacc[n][2] *= c2; oacc[n][3] *= c3;
        }

        // ---- O += P @ Vt^T : A=P (q rows), B=Vt (d rows) ----
        const bf16x8 pa0 = ldfrag(&Plds[wid][fr * 64 + rb0]);
        const bf16x8 pa1 = ldfrag(&Plds[wid][fr * 64 + rb1]);
#pragma unroll
        for (int n = 0; n < 4; ++n) {
            const bf16x8 v0 = ldfrag(&Vlds[cb][(n * 16 + fr) * 64 + rb0]);
            const bf16x8 v1 = ldfrag(&Vlds[cb][(n * 16 + fr) * 64 + rb1]);
            oacc[n] = __builtin_amdgcn_mfma_f32_16x16x32_bf16(pa0, v0, oacc[n], 0, 0, 0);
            oacc[n] = __builtin_amdgcn_mfma_f32_16x16x32_bf16(pa1, v1, oacc[n], 0, 0, 0);
        }

        __syncthreads();  // staged next tile complete; all waves done with cb
    }

    // ---- epilogue ----
    const float rinv = 1.f / lrun;
    const float i0 = __shfl(rinv, 20 * fq + 0);
    const float i1 = __shfl(rinv, 20 * fq + 1);
    const float i2 = __shfl(rinv, 20 * fq + 2);
    const float i3 = __shfl(rinv, 20 * fq + 3);
#pragma unroll
    for (int n = 0; n < 4; ++n) {
        const size_t base = (size_t)(q0 + wid * 16 + fq * 4) * 1024 + h * 64 + n * 16 + fr;
        y[base]          = f2bf(oacc[n][0] * i0);
        y[base + 1024]   = f2bf(oacc[n][1] * i1);
        y[base + 2048]   = f2bf(oacc[n][2] * i2);
        y[base + 3072]   = f2bf(oacc[n][3] * i3);
    }
}

// ---------------------------------------------------------------------------
extern "C" void kernel_launch(void* const* d_in, const int* in_sizes, int n_in,
                              void* d_out, int out_size, void* d_ws, size_t ws_size,
                              hipStream_t stream)
{
    const float* x       = (const float*)d_in[0];
    const float* W_qkv   = (const float*)d_in[1];
    const float* b_qkv   = (const float*)d_in[2];
    const float* rotary  = (const float*)d_in[3];
    const float* W_dense = (const float*)d_in[4];
    const float* b_dense = (const float*)d_in[5];
    float* out = (float*)d_out;

    char* w = (char*)d_ws;
    unsigned short* qkv_bf  = (unsigned short*)(w);              // 12,582,912 B
    unsigned short* qrot_bf = (unsigned short*)(w + 12582912);   //  4,194,304
    unsigned short* y_bf    = (unsigned short*)(w + 16777216);   //  4,194,304
    unsigned short* x_bf    = (unsigned short*)(w + 20971520);   //  4,194,304
    unsigned short* wq_bf   = (unsigned short*)(w + 25165824);   //  6,291,456
    unsigned short* rot_t   = (unsigned short*)(w + 31457280);   //  2,097,152
    unsigned short* wd_bf   = (unsigned short*)(w + 33554432);   //  2,097,152
    unsigned short* vt      = (unsigned short*)(w + 35651584);   //  4,194,304

    cast_f32_bf16<<<2048, 256, 0, stream>>>(x, x_bf, 2048 * 1024 / 4);
    cast_f32_bf16<<<3072, 256, 0, stream>>>(W_qkv, wq_bf, 3072 * 1024 / 4);
    cast_f32_bf16<<<1024, 256, 0, stream>>>(W_dense, wd_bf, 1024 * 1024 / 4);
    cast_transpose_bf16<<<dim3(16, 16), 256, 0, stream>>>(rotary, rot_t);

    // 1) qkv = x @ W_qkv^T + b_qkv -> bf16
    gemm_bf16mfma<128, 128, 2, 2, true, true><<<dim3(24, 16), 256, 0, stream>>>(
        x_bf, 1024, wq_bf, 1024, b_qkv, qkv_bf, 3072, 1024);

    // 2) vt = V^T
    transpose_v<<<dim3(32, 16), 256, 0, stream>>>(qkv_bf, vt);

    // 3) qrot = q @ rot_t^T -> bf16
    gemm_bf16mfma<128, 64, 4, 1, true, false><<<dim3(16, 16), 256, 0, stream>>>(
        qkv_bf, 3072, rot_t, 1024, nullptr, qrot_bf, 1024, 1024);

    // 4) attention
    attn_mfma<<<dim3(32, 16), 256, 0, stream>>>(qrot_bf, qkv_bf, vt, y_bf);

    // 5) out = y @ W_dense^T + b_dense -> fp32
    gemm_bf16mfma<128, 64, 4, 1, false, true><<<dim3(16, 16), 256, 0, stream>>>(
        y_bf, 1024, wd_bf, 1024, b_dense, out, 1024, 1024);
}

// Round 4
// 132.403 us; speedup vs baseline: 5.3192x; 1.0419x over previous
//
#include <hip/hip_runtime.h>
#include <math.h>

// B=1, S=2048, E=1024, nh=16, hs=64.
// Pipeline:
//   fused_cast: x,W_qkv,W_dense -> bf16; rotary -> bf16 transposed [N,K]
//   1. qkv_bf  = x @ W_qkv^T + b_qkv      (NT MFMA) -> bf16
//   2. vt      = transpose(V part)        -> [1024][2048] bf16
//   3. qrot_bf = (q @ rot_t^T) * 0.125*log2(e)  (NT MFMA) -> bf16
//   4. y_bf    = MFMA flash attention (log2-domain softmax, defer-max)
//   5. out     = y @ W_dense^T + b_dense  (NT MFMA) -> fp32

typedef float  f32x4  __attribute__((ext_vector_type(4)));
typedef __bf16 bf16x8 __attribute__((ext_vector_type(8)));
typedef __bf16 bf16x4 __attribute__((ext_vector_type(4)));

__device__ __forceinline__ unsigned short f2bf(float f) {
    unsigned int u = __builtin_bit_cast(unsigned int, f);
    u += 0x7FFFu + ((u >> 16) & 1u);            // RNE
    return (unsigned short)(u >> 16);
}
__device__ __forceinline__ void glds16(const unsigned short* g, unsigned short* l) {
    __builtin_amdgcn_global_load_lds(
        (const __attribute__((address_space(1))) void*)g,
        (__attribute__((address_space(3))) void*)l, 16, 0, 0);
}
__device__ __forceinline__ bf16x8 ldfrag(const unsigned short* p) {
    return __builtin_bit_cast(bf16x8, *(const int4*)p);
}

// ---------------------------------------------------------------------------
// bf16 MFMA GEMM, NT: C[M,N] = A[M,K] * B[N,K]^T (+bias)(*scale).
// ---------------------------------------------------------------------------
template <int BM, int BN, int WGM, int WGN, bool OUT_BF16, bool HAS_BIAS, bool SCALE_Q>
__global__ __launch_bounds__(256) void gemm_bf16mfma(
    const unsigned short* __restrict__ A, int lda,
    const unsigned short* __restrict__ B, int ldb,
    const float* __restrict__ bias,
    void* __restrict__ Cv, int ldc, int K)
{
    constexpr int WM = BM / WGM, WN = BN / WGN;
    constexpr int FM = WM / 16, FN = WN / 16;
    __shared__ unsigned short As[BM * 32];
    __shared__ unsigned short Bs[BN * 32];

    const int t    = threadIdx.x;
    const int lane = t & 63;
    const int wid  = t >> 6;
    const int wr   = wid / WGN;
    const int wc   = wid % WGN;
    const int bm   = blockIdx.y * BM;
    const int bn   = blockIdx.x * BN;

    const int srow = t >> 2;
    const int scol = (t & 3) * 8;
    unsigned short* ldsA = As + (t & 192) * 8;
    unsigned short* ldsB = Bs + (t & 192) * 8;

    const int fr = lane & 15;
    const int fq = lane >> 4;

    f32x4 acc[FM][FN];
#pragma unroll
    for (int i = 0; i < FM; ++i)
#pragma unroll
        for (int j = 0; j < FN; ++j) acc[i][j] = (f32x4){0.f, 0.f, 0.f, 0.f};

    const size_t a_base = (size_t)(bm + srow) * lda + scol;
    const size_t b_base = (size_t)(bn + srow) * ldb + scol;

    for (int k0 = 0; k0 < K; k0 += 32) {
#pragma unroll
        for (int p = 0; p < BM / 64; ++p)
            glds16(A + a_base + (size_t)p * 64 * lda + k0, ldsA + p * 2048);
#pragma unroll
        for (int p = 0; p < BN / 64; ++p)
            glds16(B + b_base + (size_t)p * 64 * ldb + k0, ldsB + p * 2048);
        __syncthreads();

        bf16x8 aF[FM], bF[FN];
#pragma unroll
        for (int m = 0; m < FM; ++m)
            aF[m] = ldfrag(As + (wr * WM + m * 16 + fr) * 32 + fq * 8);
#pragma unroll
        for (int n = 0; n < FN; ++n)
            bF[n] = ldfrag(Bs + (wc * WN + n * 16 + fr) * 32 + fq * 8);
#pragma unroll
        for (int m = 0; m < FM; ++m)
#pragma unroll
            for (int n = 0; n < FN; ++n)
                acc[m][n] = __builtin_amdgcn_mfma_f32_16x16x32_bf16(
                    aF[m], bF[n], acc[m][n], 0, 0, 0);
        __syncthreads();
    }

#pragma unroll
    for (int m = 0; m < FM; ++m) {
        const int row0 = bm + wr * WM + m * 16 + fq * 4;
#pragma unroll
        for (int n = 0; n < FN; ++n) {
            const int col = bn + wc * WN + n * 16 + fr;
            const float bv = HAS_BIAS ? bias[col] : 0.f;
#pragma unroll
            for (int j = 0; j < 4; ++j) {
                float v = acc[m][n][j] + bv;
                if (SCALE_Q) v *= 0.18033688011112042f;  // 0.125 * log2(e)
                if (OUT_BF16)
                    ((unsigned short*)Cv)[(size_t)(row0 + j) * ldc + col] = f2bf(v);
                else
                    ((float*)Cv)[(size_t)(row0 + j) * ldc + col] = v;
            }
        }
    }
}

// ---------------------------------------------------------------------------
// Fused casts: x, W_qkv, W_dense flat fp32->bf16; rotary transpose->bf16.
// grid: [0,2048) x | [2048,5120) W_qkv | [5120,6144) W_dense | [6144,6400) rot
// ---------------------------------------------------------------------------
__global__ __launch_bounds__(256) void fused_cast(
    const float* __restrict__ x, const float* __restrict__ Wq,
    const float* __restrict__ Wd, const float* __restrict__ rot,
    unsigned short* __restrict__ x_bf, unsigned short* __restrict__ wq_bf,
    unsigned short* __restrict__ wd_bf, unsigned short* __restrict__ rot_t)
{
    __shared__ unsigned short tile[64][68];
    const int b = blockIdx.x;
    const int t = threadIdx.x;

    if (b < 6144) {
        const float* in;
        unsigned short* out;
        int i;
        if (b < 2048)      { in = x;  out = x_bf;  i = b * 256 + t; }
        else if (b < 5120) { in = Wq; out = wq_bf; i = (b - 2048) * 256 + t; }
        else               { in = Wd; out = wd_bf; i = (b - 5120) * 256 + t; }
        const float4 v = ((const float4*)in)[i];
        ushort4 o;
        o.x = f2bf(v.x); o.y = f2bf(v.y); o.z = f2bf(v.z); o.w = f2bf(v.w);
        ((ushort4*)out)[i] = o;
        return;
    }

    const int tb = b - 6144;           // 0..255
    const int bn = (tb & 15) * 64;     // col of in
    const int bk = (tb >> 4) * 64;     // row of in
    const int tr = t >> 4;
    const int tc = (t & 15) * 4;
#pragma unroll
    for (int p = 0; p < 4; ++p) {
        const int r = tr + p * 16;
        const float4 v = *(const float4*)&rot[(size_t)(bk + r) * 1024 + bn + tc];
        tile[tc + 0][r] = f2bf(v.x);
        tile[tc + 1][r] = f2bf(v.y);
        tile[tc + 2][r] = f2bf(v.z);
        tile[tc + 3][r] = f2bf(v.w);
    }
    __syncthreads();
#pragma unroll
    for (int p = 0; p < 4; ++p) {
        const int r = tr + p * 16;
        ushort4 o;
        o.x = tile[r][tc + 0];
        o.y = tile[r][tc + 1];
        o.z = tile[r][tc + 2];
        o.w = tile[r][tc + 3];
        *(ushort4*)&rot_t[(size_t)(bn + r) * 1024 + bk + tc] = o;
    }
}

// ---------------------------------------------------------------------------
// V part of qkv [2048][3072] (cols 2048..3071) -> vt [1024][2048]
// ---------------------------------------------------------------------------
__global__ __launch_bounds__(256) void transpose_v(
    const unsigned short* __restrict__ qkv, unsigned short* __restrict__ vt)
{
    __shared__ unsigned short tile[64][65];
    const int bs = blockIdx.x * 64;
    const int bc = blockIdx.y * 64;
    const int t  = threadIdx.x;

    union U8 { int4 v; unsigned short u[8]; };
#pragma unroll
    for (int p = 0; p < 2; ++p) {
        const int s = (t >> 3) + p * 32;
        const int c = (t & 7) * 8;
        U8 ld;
        ld.v = *(const int4*)&qkv[(size_t)(bs + s) * 3072 + 2048 + bc + c];
#pragma unroll
        for (int i = 0; i < 8; ++i) tile[s][c + i] = ld.u[i];
    }
    __syncthreads();
#pragma unroll
    for (int p = 0; p < 2; ++p) {
        const int r  = (t >> 3) + p * 32;
        const int sc = (t & 7) * 8;
        U8 st;
#pragma unroll
        for (int i = 0; i < 8; ++i) st.u[i] = tile[sc + i][r];
        *(int4*)&vt[(size_t)(bc + r) * 2048 + bs + sc] = st.v;
    }
}

// ---------------------------------------------------------------------------
// MFMA flash attention, log2-domain softmax with defer-max.
// qrot is PRE-SCALED by 0.125*log2(e); S = qrot.k is in log2 units.
// ---------------------------------------------------------------------------
__global__ __launch_bounds__(256) void attn_mfma(
    const unsigned short* __restrict__ qrot,  // [2048][1024], pre-scaled
    const unsigned short* __restrict__ qkv,   // [2048][3072]
    const unsigned short* __restrict__ vt,    // [1024][2048]
    unsigned short* __restrict__ y)           // [2048][1024]
{
    __shared__ unsigned short Klds[2][4096];
    __shared__ unsigned short Vlds[2][4096];
    __shared__ unsigned short Plds[4][1024];

    const int t    = threadIdx.x;
    const int lane = t & 63;
    const int wid  = t >> 6;
    const int fr   = lane & 15;
    const int fq   = lane >> 4;
    const int q0   = blockIdx.x * 64;
    const int h    = blockIdx.y;

    const int srow = t >> 3;
    const int soff = 8 * ((t & 7) ^ (srow & 7));
    unsigned short* const kdst = (unsigned short*)Klds[0] + wid * 512;
    unsigned short* const vdst = (unsigned short*)Vlds[0] + wid * 512;

    const int fr7_16 = (fr & 7) << 4;
    const int rb0 = ((fq * 16) ^ fr7_16) >> 1;
    const int rb1 = ((64 + fq * 16) ^ fr7_16) >> 1;

    bf16x8 qF[2];
#pragma unroll
    for (int kc = 0; kc < 2; ++kc)
        qF[kc] = ldfrag(&qrot[(size_t)(q0 + wid * 16 + fr) * 1024 + h * 64 + kc * 32 + fq * 8]);

    float mrun = -1e30f, lrun = 0.f;
    f32x4 oacc[4];
#pragma unroll
    for (int n = 0; n < 4; ++n) oacc[n] = (f32x4){0.f, 0.f, 0.f, 0.f};

#pragma unroll
    for (int s2 = 0; s2 < 2; ++s2) {
        glds16(qkv + (size_t)(srow + 32 * s2) * 3072 + 1024 + h * 64 + soff,
               kdst + s2 * 2048);
        glds16(vt + (size_t)(h * 64 + srow + 32 * s2) * 2048 + soff,
               vdst + s2 * 2048);
    }
    __syncthreads();

    for (int kt = 0; kt < 32; ++kt) {
        const int cb = kt & 1;
        if (kt < 31) {
            const int k0n = (kt + 1) * 64;
            const int nbo = (cb ^ 1) * 4096;
#pragma unroll
            for (int s2 = 0; s2 < 2; ++s2) {
                glds16(qkv + (size_t)(k0n + srow + 32 * s2) * 3072 + 1024 + h * 64 + soff,
                       kdst + nbo + s2 * 2048);
                glds16(vt + (size_t)(h * 64 + srow + 32 * s2) * 2048 + k0n + soff,
                       vdst + nbo + s2 * 2048);
            }
        }

        // ---- S^T = K @ Q^T (log2 units) ----
        f32x4 sacc[4];
        __builtin_amdgcn_s_setprio(1);
#pragma unroll
        for (int m = 0; m < 4; ++m) {
            const bf16x8 a0 = ldfrag(&Klds[cb][(m * 16 + fr) * 64 + rb0]);
            const bf16x8 a1 = ldfrag(&Klds[cb][(m * 16 + fr) * 64 + rb1]);
            sacc[m] = __builtin_amdgcn_mfma_f32_16x16x32_bf16(a0, qF[0],
                          (f32x4){0.f, 0.f, 0.f, 0.f}, 0, 0, 0);
            sacc[m] = __builtin_amdgcn_mfma_f32_16x16x32_bf16(a1, qF[1],
                          sacc[m], 0, 0, 0);
        }
        __builtin_amdgcn_s_setprio(0);

        // ---- online softmax, defer-max (THR=8 in log2 units) ----
        float mx = sacc[0][0];
#pragma unroll
        for (int m = 0; m < 4; ++m)
#pragma unroll
            for (int j = 0; j < 4; ++j) mx = fmaxf(mx, sacc[m][j]);
        mx = fmaxf(mx, __shfl_xor(mx, 16));
        mx = fmaxf(mx, __shfl_xor(mx, 32));

        float corr = 1.f;
        if (!__all(mx - mrun <= 8.f)) {
            const float mnew = fmaxf(mrun, mx);
            corr = exp2f(mrun - mnew);
            mrun = mnew;
            const float c0 = __shfl(corr, 20 * fq + 0);
            const float c1 = __shfl(corr, 20 * fq + 1);
            const float c2 = __shfl(corr, 20 * fq + 2);
            const float c3 = __shfl(corr, 20 * fq + 3);
#pragma unroll
            for (int n = 0; n < 4; ++n) {
                oacc[n][0] *= c0; oacc[n][1] *= c1;
                oacc[n][2] *= c2; oacc[n][3] *= c3;
            }
        }

        float ps = 0.f;
#pragma unroll
        for (int m = 0; m < 4; ++m) {
            bf16x4 pk;
            const float p0 = exp2f(sacc[m][0] - mrun); ps += p0; pk[0] = (__bf16)p0;
            const float p1 = exp2f(sacc[m][1] - mrun); ps += p1; pk[1] = (__bf16)p1;
            const float p2 = exp2f(sacc[m][2] - mrun); ps += p2; pk[2] = (__bf16)p2;
            const float p3 = exp2f(sacc[m][3] - mrun); ps += p3; pk[3] = (__bf16)p3;
            *(ushort4*)&Plds[wid][fr * 64 + (((m * 32 + fq * 8) ^ fr7_16) >> 1)] =
                __builtin_bit_cast(ushort4, pk);
        }
        ps += __shfl_xor(ps, 16);
        ps += __shfl_xor(ps, 32);
        lrun = lrun * corr + ps;

        // ---- O += P @ Vt^T ----
        const bf16x8 pa0 = ldfrag(&Plds[wid][fr * 64 + rb0]);
        const bf16x8 pa1 = ldfrag(&Plds[wid][fr * 64 + rb1]);
        __builtin_amdgcn_s_setprio(1);
#pragma unroll
        for (int n = 0; n < 4; ++n) {
            const bf16x8 v0 = ldfrag(&Vlds[cb][(n * 16 + fr) * 64 + rb0]);
            const bf16x8 v1 = ldfrag(&Vlds[cb][(n * 16 + fr) * 64 + rb1]);
            oacc[n] = __builtin_amdgcn_mfma_f32_16x16x32_bf16(pa0, v0, oacc[n], 0, 0, 0);
            oacc[n] = __builtin_amdgcn_mfma_f32_16x16x32_bf16(pa1, v1, oacc[n], 0, 0, 0);
        }
        __builtin_amdgcn_s_setprio(0);

        __syncthreads();
    }

    const float rinv = 1.f / lrun;
    const float i0 = __shfl(rinv, 20 * fq + 0);
    const float i1 = __shfl(rinv, 20 * fq + 1);
    const float i2 = __shfl(rinv, 20 * fq + 2);
    const float i3 = __shfl(rinv, 20 * fq + 3);
#pragma unroll
    for (int n = 0; n < 4; ++n) {
        const size_t base = (size_t)(q0 + wid * 16 + fq * 4) * 1024 + h * 64 + n * 16 + fr;
        y[base]          = f2bf(oacc[n][0] * i0);
        y[base + 1024]   = f2bf(oacc[n][1] * i1);
        y[base + 2048]   = f2bf(oacc[n][2] * i2);
        y[base + 3072]   = f2bf(oacc[n][3] * i3);
    }
}

// ---------------------------------------------------------------------------
extern "C" void kernel_launch(void* const* d_in, const int* in_sizes, int n_in,
                              void* d_out, int out_size, void* d_ws, size_t ws_size,
                              hipStream_t stream)
{
    const float* x       = (const float*)d_in[0];
    const float* W_qkv   = (const float*)d_in[1];
    const float* b_qkv   = (const float*)d_in[2];
    const float* rotary  = (const float*)d_in[3];
    const float* W_dense = (const float*)d_in[4];
    const float* b_dense = (const float*)d_in[5];
    float* out = (float*)d_out;

    char* w = (char*)d_ws;
    unsigned short* qkv_bf  = (unsigned short*)(w);              // 12,582,912 B
    unsigned short* qrot_bf = (unsigned short*)(w + 12582912);   //  4,194,304
    unsigned short* y_bf    = (unsigned short*)(w + 16777216);   //  4,194,304
    unsigned short* x_bf    = (unsigned short*)(w + 20971520);   //  4,194,304
    unsigned short* wq_bf   = (unsigned short*)(w + 25165824);   //  6,291,456
    unsigned short* rot_t   = (unsigned short*)(w + 31457280);   //  2,097,152
    unsigned short* wd_bf   = (unsigned short*)(w + 33554432);   //  2,097,152
    unsigned short* vt      = (unsigned short*)(w + 35651584);   //  4,194,304

    fused_cast<<<6400, 256, 0, stream>>>(x, W_qkv, W_dense, rotary,
                                         x_bf, wq_bf, wd_bf, rot_t);

    // 1) qkv = x @ W_qkv^T + b_qkv -> bf16
    gemm_bf16mfma<128, 128, 2, 2, true, true, false><<<dim3(24, 16), 256, 0, stream>>>(
        x_bf, 1024, wq_bf, 1024, b_qkv, qkv_bf, 3072, 1024);

    // 2) vt = V^T
    transpose_v<<<dim3(32, 16), 256, 0, stream>>>(qkv_bf, vt);

    // 3) qrot = (q @ rot_t^T) * 0.125*log2e -> bf16
    gemm_bf16mfma<128, 64, 4, 1, true, false, true><<<dim3(16, 16), 256, 0, stream>>>(
        qkv_bf, 3072, rot_t, 1024, nullptr, qrot_bf, 1024, 1024);

    // 4) attention
    attn_mfma<<<dim3(32, 16), 256, 0, stream>>>(qrot_bf, qkv_bf, vt, y_bf);

    // 5) out = y @ W_dense^T + b_dense -> fp32
    gemm_bf16mfma<128, 64, 4, 1, false, true, false><<<dim3(16, 16), 256, 0, stream>>>(
        y_bf, 1024, wd_bf, 1024, b_dense, out, 1024, 1024);
}

// Round 5
// 125.274 us; speedup vs baseline: 5.6220x; 1.0569x over previous
//
#include <hip/hip_runtime.h>
#include <math.h>

// B=1, S=2048, E=1024, nh=16, hs=64.
// Pipeline:
//   fused_cast: x->bf16; W_qkv[1024:3072]->w_all kv part; W_dense->bf16;
//               rotary^T->rot_t; W_qkv[0:1024]^T->wq_t
//   brot:       b_all[0:1024] = R^T b_q ; b_all[1024:3072] = b_qkv[1024:]
//   G-gemm:     w_all[0:1024] = rot_t @ wq_t^T  (= R^T Wq, folded rotary)
//   qkv-gemm:   qkv_bf = x @ w_all^T + b_all; cols<1024 scaled 0.125*log2e
//               (cols 0-1023 ARE rotated+scaled q)
//   transpose_v, attn (triple-buffered, counted vmcnt), dense gemm.

typedef float  f32x4  __attribute__((ext_vector_type(4)));
typedef __bf16 bf16x8 __attribute__((ext_vector_type(8)));
typedef __bf16 bf16x4 __attribute__((ext_vector_type(4)));

__device__ __forceinline__ unsigned short f2bf(float f) {
    unsigned int u = __builtin_bit_cast(unsigned int, f);
    u += 0x7FFFu + ((u >> 16) & 1u);            // RNE
    return (unsigned short)(u >> 16);
}
__device__ __forceinline__ float bf2f(unsigned short h) {
    return __builtin_bit_cast(float, (unsigned int)h << 16);
}
__device__ __forceinline__ void glds16(const unsigned short* g, unsigned short* l) {
    __builtin_amdgcn_global_load_lds(
        (const __attribute__((address_space(1))) void*)g,
        (__attribute__((address_space(3))) void*)l, 16, 0, 0);
}
__device__ __forceinline__ bf16x8 ldfrag(const unsigned short* p) {
    return __builtin_bit_cast(bf16x8, *(const int4*)p);
}

// ---------------------------------------------------------------------------
// bf16 MFMA GEMM, NT: C[M,N] = A[M,K] * B[N,K]^T (+bias).
// SCALE_MODE 1: multiply cols<1024 by 0.125*log2(e) after bias.
// ---------------------------------------------------------------------------
template <int BM, int BN, int WGM, int WGN, bool OUT_BF16, bool HAS_BIAS, int SCALE_MODE>
__global__ __launch_bounds__(256) void gemm_bf16mfma(
    const unsigned short* __restrict__ A, int lda,
    const unsigned short* __restrict__ B, int ldb,
    const float* __restrict__ bias,
    void* __restrict__ Cv, int ldc, int K)
{
    constexpr int WM = BM / WGM, WN = BN / WGN;
    constexpr int FM = WM / 16, FN = WN / 16;
    __shared__ unsigned short As[BM * 32];
    __shared__ unsigned short Bs[BN * 32];

    const int t    = threadIdx.x;
    const int lane = t & 63;
    const int wid  = t >> 6;
    const int wr   = wid / WGN;
    const int wc   = wid % WGN;
    const int bm   = blockIdx.y * BM;
    const int bn   = blockIdx.x * BN;

    const int srow = t >> 2;
    const int scol = (t & 3) * 8;
    unsigned short* ldsA = As + (t & 192) * 8;
    unsigned short* ldsB = Bs + (t & 192) * 8;

    const int fr = lane & 15;
    const int fq = lane >> 4;

    f32x4 acc[FM][FN];
#pragma unroll
    for (int i = 0; i < FM; ++i)
#pragma unroll
        for (int j = 0; j < FN; ++j) acc[i][j] = (f32x4){0.f, 0.f, 0.f, 0.f};

    const size_t a_base = (size_t)(bm + srow) * lda + scol;
    const size_t b_base = (size_t)(bn + srow) * ldb + scol;

    for (int k0 = 0; k0 < K; k0 += 32) {
#pragma unroll
        for (int p = 0; p < BM / 64; ++p)
            glds16(A + a_base + (size_t)p * 64 * lda + k0, ldsA + p * 2048);
#pragma unroll
        for (int p = 0; p < BN / 64; ++p)
            glds16(B + b_base + (size_t)p * 64 * ldb + k0, ldsB + p * 2048);
        __syncthreads();

        bf16x8 aF[FM], bF[FN];
#pragma unroll
        for (int m = 0; m < FM; ++m)
            aF[m] = ldfrag(As + (wr * WM + m * 16 + fr) * 32 + fq * 8);
#pragma unroll
        for (int n = 0; n < FN; ++n)
            bF[n] = ldfrag(Bs + (wc * WN + n * 16 + fr) * 32 + fq * 8);
#pragma unroll
        for (int m = 0; m < FM; ++m)
#pragma unroll
            for (int n = 0; n < FN; ++n)
                acc[m][n] = __builtin_amdgcn_mfma_f32_16x16x32_bf16(
                    aF[m], bF[n], acc[m][n], 0, 0, 0);
        __syncthreads();
    }

#pragma unroll
    for (int m = 0; m < FM; ++m) {
        const int row0 = bm + wr * WM + m * 16 + fq * 4;
#pragma unroll
        for (int n = 0; n < FN; ++n) {
            const int col = bn + wc * WN + n * 16 + fr;
            const float bv = HAS_BIAS ? bias[col] : 0.f;
#pragma unroll
            for (int j = 0; j < 4; ++j) {
                float v = acc[m][n][j] + bv;
                if (SCALE_MODE == 1 && col < 1024)
                    v *= 0.18033688011112042f;  // 0.125 * log2(e)
                if (OUT_BF16)
                    ((unsigned short*)Cv)[(size_t)(row0 + j) * ldc + col] = f2bf(v);
                else
                    ((float*)Cv)[(size_t)(row0 + j) * ldc + col] = v;
            }
        }
    }
}

// ---------------------------------------------------------------------------
// Fused casts / transposes.
// [0,2048) x->x_bf | [2048,4096) Wqkv rows 1024..3071 -> w_all kv part
// [4096,5120) W_dense->wd_bf | [5120,5376) rotary^T->rot_t
// [5376,5632) Wq rows 0..1023 ^T -> wq_t
// ---------------------------------------------------------------------------
__global__ __launch_bounds__(256) void fused_cast(
    const float* __restrict__ x, const float* __restrict__ Wq,
    const float* __restrict__ Wd, const float* __restrict__ rot,
    unsigned short* __restrict__ x_bf, unsigned short* __restrict__ w_all,
    unsigned short* __restrict__ wd_bf, unsigned short* __restrict__ rot_t,
    unsigned short* __restrict__ wq_t)
{
    __shared__ unsigned short tile[64][68];
    const int b = blockIdx.x;
    const int t = threadIdx.x;

    if (b < 5120) {
        const float4* in;
        ushort4* out;
        int i;
        if (b < 2048) {
            in = (const float4*)x;               out = (ushort4*)x_bf;
            i = b * 256 + t;
        } else if (b < 4096) {
            in = (const float4*)Wq + 262144;     out = (ushort4*)w_all + 262144;
            i = (b - 2048) * 256 + t;
        } else {
            in = (const float4*)Wd;              out = (ushort4*)wd_bf;
            i = (b - 4096) * 256 + t;
        }
        const float4 v = in[i];
        ushort4 o;
        o.x = f2bf(v.x); o.y = f2bf(v.y); o.z = f2bf(v.z); o.w = f2bf(v.w);
        out[i] = o;
        return;
    }

    const bool is_rot = (b < 5376);
    const float* in          = is_rot ? rot   : Wq;
    unsigned short* out      = is_rot ? rot_t : wq_t;
    const int tb = (b - 5120) & 255;
    const int bn = (tb & 15) * 64;     // col of in
    const int bk = (tb >> 4) * 64;     // row of in
    const int tr = t >> 4;
    const int tc = (t & 15) * 4;
#pragma unroll
    for (int p = 0; p < 4; ++p) {
        const int r = tr + p * 16;
        const float4 v = *(const float4*)&in[(size_t)(bk + r) * 1024 + bn + tc];
        tile[tc + 0][r] = f2bf(v.x);
        tile[tc + 1][r] = f2bf(v.y);
        tile[tc + 2][r] = f2bf(v.z);
        tile[tc + 3][r] = f2bf(v.w);
    }
    __syncthreads();
#pragma unroll
    for (int p = 0; p < 4; ++p) {
        const int r = tr + p * 16;
        ushort4 o;
        o.x = tile[r][tc + 0];
        o.y = tile[r][tc + 1];
        o.z = tile[r][tc + 2];
        o.w = tile[r][tc + 3];
        *(ushort4*)&out[(size_t)(bn + r) * 1024 + bk + tc] = o;
    }
}

// ---------------------------------------------------------------------------
// b_all[d<1024] = sum_e rot_t[d][e] * b_qkv[e]  (= R^T b_q, one wave per d)
// b_all[1024..3071] = b_qkv[1024..3071]
// ---------------------------------------------------------------------------
__global__ __launch_bounds__(256) void brot_kernel(
    const unsigned short* __restrict__ rot_t, const float* __restrict__ b_qkv,
    float* __restrict__ b_all)
{
    const int b = blockIdx.x;
    const int t = threadIdx.x;
    if (b < 256) {
        const int d = b * 4 + (t >> 6);
        const int l = t & 63;
        float acc = 0.f;
#pragma unroll
        for (int i = 0; i < 16; ++i) {
            const int e = i * 64 + l;
            acc += bf2f(rot_t[(size_t)d * 1024 + e]) * b_qkv[e];
        }
#pragma unroll
        for (int off = 1; off < 64; off <<= 1) acc += __shfl_xor(acc, off);
        if (l == 0) b_all[d] = acc;
    } else {
        const int idx = 1024 + (b - 256) * 256 + t;
        b_all[idx] = b_qkv[idx];
    }
}

// ---------------------------------------------------------------------------
// V part of qkv [2048][3072] (cols 2048..3071) -> vt [1024][2048]
// ---------------------------------------------------------------------------
__global__ __launch_bounds__(256) void transpose_v(
    const unsigned short* __restrict__ qkv, unsigned short* __restrict__ vt)
{
    __shared__ unsigned short tile[64][65];
    const int bs = blockIdx.x * 64;
    const int bc = blockIdx.y * 64;
    const int t  = threadIdx.x;

    union U8 { int4 v; unsigned short u[8]; };
#pragma unroll
    for (int p = 0; p < 2; ++p) {
        const int s = (t >> 3) + p * 32;
        const int c = (t & 7) * 8;
        U8 ld;
        ld.v = *(const int4*)&qkv[(size_t)(bs + s) * 3072 + 2048 + bc + c];
#pragma unroll
        for (int i = 0; i < 8; ++i) tile[s][c + i] = ld.u[i];
    }
    __syncthreads();
#pragma unroll
    for (int p = 0; p < 2; ++p) {
        const int r  = (t >> 3) + p * 32;
        const int sc = (t & 7) * 8;
        U8 st;
#pragma unroll
        for (int i = 0; i < 8; ++i) st.u[i] = tile[sc + i][r];
        *(int4*)&vt[(size_t)(bc + r) * 2048 + bs + sc] = st.v;
    }
}

// ---------------------------------------------------------------------------
// MFMA flash attention. Triple-buffered K/V (2-tiles-ahead prefetch),
// counted s_waitcnt vmcnt(4) + raw s_barrier (never drain to 0 in loop).
// qrot lives in qkv cols 0..1023, pre-scaled by 0.125*log2e.
// ---------------------------------------------------------------------------
__global__ __launch_bounds__(256) void attn_mfma(
    const unsigned short* __restrict__ qkv,   // [2048][3072]
    const unsigned short* __restrict__ vt,    // [1024][2048]
    unsigned short* __restrict__ y)           // [2048][1024]
{
    __shared__ unsigned short Klds[3][4096];
    __shared__ unsigned short Vlds[3][4096];
    __shared__ unsigned short Plds[4][1024];

    const int t    = threadIdx.x;
    const int lane = t & 63;
    const int wid  = t >> 6;
    const int fr   = lane & 15;
    const int fq   = lane >> 4;
    const int q0   = blockIdx.x * 64;
    const int h    = blockIdx.y;

    const int srow = t >> 3;                      // 0..31
    const int soff = 8 * ((t & 7) ^ (srow & 7));  // pre-swizzled source col

    const int fr7_16 = (fr & 7) << 4;
    const int rb0 = ((fq * 16) ^ fr7_16) >> 1;
    const int rb1 = ((64 + fq * 16) ^ fr7_16) >> 1;

    bf16x8 qF[2];
#pragma unroll
    for (int kc = 0; kc < 2; ++kc)
        qF[kc] = ldfrag(&qkv[(size_t)(q0 + wid * 16 + fr) * 3072 + h * 64 + kc * 32 + fq * 8]);

    auto stage = [&](int kt_, int b_) {
#pragma unroll
        for (int s2 = 0; s2 < 2; ++s2) {
            glds16(qkv + (size_t)(kt_ * 64 + srow + 32 * s2) * 3072 + 1024 + h * 64 + soff,
                   &Klds[b_][wid * 512 + s2 * 2048]);
            glds16(vt + (size_t)(h * 64 + srow + 32 * s2) * 2048 + kt_ * 64 + soff,
                   &Vlds[b_][wid * 512 + s2 * 2048]);
        }
    };

    float mrun = -1e30f, lrun = 0.f;
    f32x4 oacc[4];
#pragma unroll
    for (int n = 0; n < 4; ++n) oacc[n] = (f32x4){0.f, 0.f, 0.f, 0.f};

    stage(0, 0);
    stage(1, 1);

    for (int kt = 0; kt < 32; ++kt) {
        const int cb = kt % 3;
        // wait for THIS tile's 4 staging loads (newest 4 = next tile's stay in flight)
        if (kt < 31) asm volatile("s_waitcnt vmcnt(4)" ::: "memory");
        else         asm volatile("s_waitcnt vmcnt(0)" ::: "memory");
        __builtin_amdgcn_s_barrier();   // all waves: tile ready + done reading buf (kt+2)%3
        if (kt < 30) stage(kt + 2, (kt + 2) % 3);

        // ---- S^T = K @ Q^T (log2 units) ----
        f32x4 sacc[4];
        __builtin_amdgcn_s_setprio(1);
#pragma unroll
        for (int m = 0; m < 4; ++m) {
            const bf16x8 a0 = ldfrag(&Klds[cb][(m * 16 + fr) * 64 + rb0]);
            const bf16x8 a1 = ldfrag(&Klds[cb][(m * 16 + fr) * 64 + rb1]);
            sacc[m] = __builtin_amdgcn_mfma_f32_16x16x32_bf16(a0, qF[0],
                          (f32x4){0.f, 0.f, 0.f, 0.f}, 0, 0, 0);
            sacc[m] = __builtin_amdgcn_mfma_f32_16x16x32_bf16(a1, qF[1],
                          sacc[m], 0, 0, 0);
        }
        __builtin_amdgcn_s_setprio(0);

        // ---- online softmax, defer-max (THR=8 in log2 units) ----
        float mx = sacc[0][0];
#pragma unroll
        for (int m = 0; m < 4; ++m)
#pragma unroll
            for (int j = 0; j < 4; ++j) mx = fmaxf(mx, sacc[m][j]);
        mx = fmaxf(mx, __shfl_xor(mx, 16));
        mx = fmaxf(mx, __shfl_xor(mx, 32));

        float corr = 1.f;
        if (!__all(mx - mrun <= 8.f)) {
            const float mnew = fmaxf(mrun, mx);
            corr = exp2f(mrun - mnew);
            mrun = mnew;
            const float c0 = __shfl(corr, 20 * fq + 0);
            const float c1 = __shfl(corr, 20 * fq + 1);
            const float c2 = __shfl(corr, 20 * fq + 2);
            const float c3 = __shfl(corr, 20 * fq + 3);
#pragma unroll
            for (int n = 0; n < 4; ++n) {
                oacc[n][0] *= c0; oacc[n][1] *= c1;
                oacc[n][2] *= c2; oacc[n][3] *= c3;
            }
        }

        float ps = 0.f;
#pragma unroll
        for (int m = 0; m < 4; ++m) {
            bf16x4 pk;
            const float p0 = exp2f(sacc[m][0] - mrun); ps += p0; pk[0] = (__bf16)p0;
            const float p1 = exp2f(sacc[m][1] - mrun); ps += p1; pk[1] = (__bf16)p1;
            const float p2 = exp2f(sacc[m][2] - mrun); ps += p2; pk[2] = (__bf16)p2;
            const float p3 = exp2f(sacc[m][3] - mrun); ps += p3; pk[3] = (__bf16)p3;
            *(ushort4*)&Plds[wid][fr * 64 + (((m * 32 + fq * 8) ^ fr7_16) >> 1)] =
                __builtin_bit_cast(ushort4, pk);
        }
        ps += __shfl_xor(ps, 16);
        ps += __shfl_xor(ps, 32);
        lrun = lrun * corr + ps;

        // ---- O += P @ Vt^T ----
        const bf16x8 pa0 = ldfrag(&Plds[wid][fr * 64 + rb0]);
        const bf16x8 pa1 = ldfrag(&Plds[wid][fr * 64 + rb1]);
        __builtin_amdgcn_s_setprio(1);
#pragma unroll
        for (int n = 0; n < 4; ++n) {
            const bf16x8 v0 = ldfrag(&Vlds[cb][(n * 16 + fr) * 64 + rb0]);
            const bf16x8 v1 = ldfrag(&Vlds[cb][(n * 16 + fr) * 64 + rb1]);
            oacc[n] = __builtin_amdgcn_mfma_f32_16x16x32_bf16(pa0, v0, oacc[n], 0, 0, 0);
            oacc[n] = __builtin_amdgcn_mfma_f32_16x16x32_bf16(pa1, v1, oacc[n], 0, 0, 0);
        }
        __builtin_amdgcn_s_setprio(0);
    }

    const float rinv = 1.f / lrun;
    const float i0 = __shfl(rinv, 20 * fq + 0);
    const float i1 = __shfl(rinv, 20 * fq + 1);
    const float i2 = __shfl(rinv, 20 * fq + 2);
    const float i3 = __shfl(rinv, 20 * fq + 3);
#pragma unroll
    for (int n = 0; n < 4; ++n) {
        const size_t base = (size_t)(q0 + wid * 16 + fq * 4) * 1024 + h * 64 + n * 16 + fr;
        y[base]          = f2bf(oacc[n][0] * i0);
        y[base + 1024]   = f2bf(oacc[n][1] * i1);
        y[base + 2048]   = f2bf(oacc[n][2] * i2);
        y[base + 3072]   = f2bf(oacc[n][3] * i3);
    }
}

// ---------------------------------------------------------------------------
extern "C" void kernel_launch(void* const* d_in, const int* in_sizes, int n_in,
                              void* d_out, int out_size, void* d_ws, size_t ws_size,
                              hipStream_t stream)
{
    const float* x       = (const float*)d_in[0];
    const float* W_qkv   = (const float*)d_in[1];
    const float* b_qkv   = (const float*)d_in[2];
    const float* rotary  = (const float*)d_in[3];
    const float* W_dense = (const float*)d_in[4];
    const float* b_dense = (const float*)d_in[5];
    float* out = (float*)d_out;

    char* w = (char*)d_ws;
    unsigned short* w_all   = (unsigned short*)(w);              //  6,291,456 B
    unsigned short* qkv_bf  = (unsigned short*)(w + 6291456);    // 12,582,912
    unsigned short* y_bf    = (unsigned short*)(w + 18874368);   //  4,194,304
    unsigned short* x_bf    = (unsigned short*)(w + 23068672);   //  4,194,304
    unsigned short* rot_t   = (unsigned short*)(w + 27262976);   //  2,097,152
    unsigned short* wq_t    = (unsigned short*)(w + 29360128);   //  2,097,152
    unsigned short* wd_bf   = (unsigned short*)(w + 31457280);   //  2,097,152
    unsigned short* vt      = (unsigned short*)(w + 33554432);   //  4,194,304
    float*          b_all   = (float*)(w + 37748736);            //     12,288

    fused_cast<<<5632, 256, 0, stream>>>(x, W_qkv, W_dense, rotary,
                                         x_bf, w_all, wd_bf, rot_t, wq_t);
    brot_kernel<<<264, 256, 0, stream>>>(rot_t, b_qkv, b_all);

    // G = R^T Wq -> w_all rows 0..1023
    gemm_bf16mfma<64, 64, 2, 2, true, false, 0><<<dim3(16, 16), 256, 0, stream>>>(
        rot_t, 1024, wq_t, 1024, nullptr, w_all, 1024, 1024);

    // qkv = x @ w_all^T + b_all ; cols<1024 (rotated q) scaled by 0.125*log2e
    gemm_bf16mfma<64, 128, 2, 2, true, true, 1><<<dim3(24, 32), 256, 0, stream>>>(
        x_bf, 1024, w_all, 1024, b_all, qkv_bf, 3072, 1024);

    transpose_v<<<dim3(32, 16), 256, 0, stream>>>(qkv_bf, vt);

    attn_mfma<<<dim3(32, 16), 256, 0, stream>>>(qkv_bf, vt, y_bf);

    gemm_bf16mfma<128, 64, 4, 1, false, true, 0><<<dim3(16, 16), 256, 0, stream>>>(
        y_bf, 1024, wd_bf, 1024, b_dense, out, 1024, 1024);
}

// Round 6
// 111.567 us; speedup vs baseline: 6.3126x; 1.1229x over previous
//
#include <hip/hip_runtime.h>
#include <math.h>

// B=1, S=2048, E=1024, nh=16, hs=64.
// Pipeline:
//   fused_cast: x->bf16; W_qkv[1024:3072]->w_all kv part; W_dense->bf16;
//               rotary^T->rot_t; W_qkv[0:1024]^T->wq_t
//   brot:       b_all[0:1024] = R^T b_q ; rest copied
//   G-gemm:     w_all[0:1024] = rot_t @ wq_t^T  (= R^T Wq, folded rotary)
//   qkv-gemm:   qkv_bf = x @ w_all^T + b_all; cols<1024 scaled 0.125*log2e
//   transpose_v, attn (KV-split 2-way, fixed-shift softmax, partials),
//   merge, dense gemm.

typedef float  f32x4  __attribute__((ext_vector_type(4)));
typedef __bf16 bf16x8 __attribute__((ext_vector_type(8)));
typedef __bf16 bf16x4 __attribute__((ext_vector_type(4)));

__device__ __forceinline__ unsigned short f2bf(float f) {
    unsigned int u = __builtin_bit_cast(unsigned int, f);
    u += 0x7FFFu + ((u >> 16) & 1u);            // RNE
    return (unsigned short)(u >> 16);
}
__device__ __forceinline__ float bf2f(unsigned short h) {
    return __builtin_bit_cast(float, (unsigned int)h << 16);
}
__device__ __forceinline__ void glds16(const unsigned short* g, unsigned short* l) {
    __builtin_amdgcn_global_load_lds(
        (const __attribute__((address_space(1))) void*)g,
        (__attribute__((address_space(3))) void*)l, 16, 0, 0);
}
__device__ __forceinline__ bf16x8 ldfrag(const unsigned short* p) {
    return __builtin_bit_cast(bf16x8, *(const int4*)p);
}

// ---------------------------------------------------------------------------
// bf16 MFMA GEMM, NT: C[M,N] = A[M,K] * B[N,K]^T (+bias).
// SCALE_MODE 1: multiply cols<1024 by 0.125*log2(e) after bias.
// ---------------------------------------------------------------------------
template <int BM, int BN, int WGM, int WGN, bool OUT_BF16, bool HAS_BIAS, int SCALE_MODE>
__global__ __launch_bounds__(256) void gemm_bf16mfma(
    const unsigned short* __restrict__ A, int lda,
    const unsigned short* __restrict__ B, int ldb,
    const float* __restrict__ bias,
    void* __restrict__ Cv, int ldc, int K)
{
    constexpr int WM = BM / WGM, WN = BN / WGN;
    constexpr int FM = WM / 16, FN = WN / 16;
    __shared__ unsigned short As[BM * 32];
    __shared__ unsigned short Bs[BN * 32];

    const int t    = threadIdx.x;
    const int lane = t & 63;
    const int wid  = t >> 6;
    const int wr   = wid / WGN;
    const int wc   = wid % WGN;
    const int bm   = blockIdx.y * BM;
    const int bn   = blockIdx.x * BN;

    const int srow = t >> 2;
    const int scol = (t & 3) * 8;
    unsigned short* ldsA = As + (t & 192) * 8;
    unsigned short* ldsB = Bs + (t & 192) * 8;

    const int fr = lane & 15;
    const int fq = lane >> 4;

    f32x4 acc[FM][FN];
#pragma unroll
    for (int i = 0; i < FM; ++i)
#pragma unroll
        for (int j = 0; j < FN; ++j) acc[i][j] = (f32x4){0.f, 0.f, 0.f, 0.f};

    const size_t a_base = (size_t)(bm + srow) * lda + scol;
    const size_t b_base = (size_t)(bn + srow) * ldb + scol;

    for (int k0 = 0; k0 < K; k0 += 32) {
#pragma unroll
        for (int p = 0; p < BM / 64; ++p)
            glds16(A + a_base + (size_t)p * 64 * lda + k0, ldsA + p * 2048);
#pragma unroll
        for (int p = 0; p < BN / 64; ++p)
            glds16(B + b_base + (size_t)p * 64 * ldb + k0, ldsB + p * 2048);
        __syncthreads();

        bf16x8 aF[FM], bF[FN];
#pragma unroll
        for (int m = 0; m < FM; ++m)
            aF[m] = ldfrag(As + (wr * WM + m * 16 + fr) * 32 + fq * 8);
#pragma unroll
        for (int n = 0; n < FN; ++n)
            bF[n] = ldfrag(Bs + (wc * WN + n * 16 + fr) * 32 + fq * 8);
#pragma unroll
        for (int m = 0; m < FM; ++m)
#pragma unroll
            for (int n = 0; n < FN; ++n)
                acc[m][n] = __builtin_amdgcn_mfma_f32_16x16x32_bf16(
                    aF[m], bF[n], acc[m][n], 0, 0, 0);
        __syncthreads();
    }

#pragma unroll
    for (int m = 0; m < FM; ++m) {
        const int row0 = bm + wr * WM + m * 16 + fq * 4;
#pragma unroll
        for (int n = 0; n < FN; ++n) {
            const int col = bn + wc * WN + n * 16 + fr;
            const float bv = HAS_BIAS ? bias[col] : 0.f;
#pragma unroll
            for (int j = 0; j < 4; ++j) {
                float v = acc[m][n][j] + bv;
                if (SCALE_MODE == 1 && col < 1024)
                    v *= 0.18033688011112042f;  // 0.125 * log2(e)
                if (OUT_BF16)
                    ((unsigned short*)Cv)[(size_t)(row0 + j) * ldc + col] = f2bf(v);
                else
                    ((float*)Cv)[(size_t)(row0 + j) * ldc + col] = v;
            }
        }
    }
}

// ---------------------------------------------------------------------------
// Fused casts / transposes.
// [0,2048) x->x_bf | [2048,4096) Wqkv rows 1024..3071 -> w_all kv part
// [4096,5120) W_dense->wd_bf | [5120,5376) rotary^T->rot_t
// [5376,5632) Wq rows 0..1023 ^T -> wq_t
// ---------------------------------------------------------------------------
__global__ __launch_bounds__(256) void fused_cast(
    const float* __restrict__ x, const float* __restrict__ Wq,
    const float* __restrict__ Wd, const float* __restrict__ rot,
    unsigned short* __restrict__ x_bf, unsigned short* __restrict__ w_all,
    unsigned short* __restrict__ wd_bf, unsigned short* __restrict__ rot_t,
    unsigned short* __restrict__ wq_t)
{
    __shared__ unsigned short tile[64][68];
    const int b = blockIdx.x;
    const int t = threadIdx.x;

    if (b < 5120) {
        const float4* in;
        ushort4* out;
        int i;
        if (b < 2048) {
            in = (const float4*)x;               out = (ushort4*)x_bf;
            i = b * 256 + t;
        } else if (b < 4096) {
            in = (const float4*)Wq + 262144;     out = (ushort4*)w_all + 262144;
            i = (b - 2048) * 256 + t;
        } else {
            in = (const float4*)Wd;              out = (ushort4*)wd_bf;
            i = (b - 4096) * 256 + t;
        }
        const float4 v = in[i];
        ushort4 o;
        o.x = f2bf(v.x); o.y = f2bf(v.y); o.z = f2bf(v.z); o.w = f2bf(v.w);
        out[i] = o;
        return;
    }

    const bool is_rot = (b < 5376);
    const float* in          = is_rot ? rot   : Wq;
    unsigned short* out      = is_rot ? rot_t : wq_t;
    const int tb = (b - 5120) & 255;
    const int bn = (tb & 15) * 64;
    const int bk = (tb >> 4) * 64;
    const int tr = t >> 4;
    const int tc = (t & 15) * 4;
#pragma unroll
    for (int p = 0; p < 4; ++p) {
        const int r = tr + p * 16;
        const float4 v = *(const float4*)&in[(size_t)(bk + r) * 1024 + bn + tc];
        tile[tc + 0][r] = f2bf(v.x);
        tile[tc + 1][r] = f2bf(v.y);
        tile[tc + 2][r] = f2bf(v.z);
        tile[tc + 3][r] = f2bf(v.w);
    }
    __syncthreads();
#pragma unroll
    for (int p = 0; p < 4; ++p) {
        const int r = tr + p * 16;
        ushort4 o;
        o.x = tile[r][tc + 0];
        o.y = tile[r][tc + 1];
        o.z = tile[r][tc + 2];
        o.w = tile[r][tc + 3];
        *(ushort4*)&out[(size_t)(bn + r) * 1024 + bk + tc] = o;
    }
}

// ---------------------------------------------------------------------------
// b_all[d<1024] = R^T b_q ; b_all[1024..3071] = b_qkv[1024..3071]
// ---------------------------------------------------------------------------
__global__ __launch_bounds__(256) void brot_kernel(
    const unsigned short* __restrict__ rot_t, const float* __restrict__ b_qkv,
    float* __restrict__ b_all)
{
    const int b = blockIdx.x;
    const int t = threadIdx.x;
    if (b < 256) {
        const int d = b * 4 + (t >> 6);
        const int l = t & 63;
        float acc = 0.f;
#pragma unroll
        for (int i = 0; i < 16; ++i) {
            const int e = i * 64 + l;
            acc += bf2f(rot_t[(size_t)d * 1024 + e]) * b_qkv[e];
        }
#pragma unroll
        for (int off = 1; off < 64; off <<= 1) acc += __shfl_xor(acc, off);
        if (l == 0) b_all[d] = acc;
    } else {
        const int idx = 1024 + (b - 256) * 256 + t;
        b_all[idx] = b_qkv[idx];
    }
}

// ---------------------------------------------------------------------------
// V part of qkv [2048][3072] (cols 2048..3071) -> vt [1024][2048]
// ---------------------------------------------------------------------------
__global__ __launch_bounds__(256) void transpose_v(
    const unsigned short* __restrict__ qkv, unsigned short* __restrict__ vt)
{
    __shared__ unsigned short tile[64][65];
    const int bs = blockIdx.x * 64;
    const int bc = blockIdx.y * 64;
    const int t  = threadIdx.x;

    union U8 { int4 v; unsigned short u[8]; };
#pragma unroll
    for (int p = 0; p < 2; ++p) {
        const int s = (t >> 3) + p * 32;
        const int c = (t & 7) * 8;
        U8 ld;
        ld.v = *(const int4*)&qkv[(size_t)(bs + s) * 3072 + 2048 + bc + c];
#pragma unroll
        for (int i = 0; i < 8; ++i) tile[s][c + i] = ld.u[i];
    }
    __syncthreads();
#pragma unroll
    for (int p = 0; p < 2; ++p) {
        const int r  = (t >> 3) + p * 32;
        const int sc = (t & 7) * 8;
        U8 st;
#pragma unroll
        for (int i = 0; i < 8; ++i) st.u[i] = tile[sc + i][r];
        *(int4*)&vt[(size_t)(bc + r) * 2048 + bs + sc] = st.v;
    }
}

// ---------------------------------------------------------------------------
// MFMA flash attention, KV-split 2-way (blockIdx.z = split of 1024 keys).
// Fixed-shift softmax (c=0): P = exp2(S); partials combine by addition.
// Writes unnormalized partial O (bf16) + per-row l sums.
// LDS 40KB -> 4 blocks/CU.
// ---------------------------------------------------------------------------
__global__ __launch_bounds__(256) void attn_mfma(
    const unsigned short* __restrict__ qkv,   // [2048][3072] (q pre-scaled)
    const unsigned short* __restrict__ vt,    // [1024][2048]
    unsigned short* __restrict__ partialO,    // [2][2048][1024] bf16
    float* __restrict__ lsum)                 // [2][16][2048]
{
    __shared__ unsigned short Klds[2][4096];
    __shared__ unsigned short Vlds[2][4096];
    __shared__ unsigned short Plds[4][1024];

    const int t     = threadIdx.x;
    const int lane  = t & 63;
    const int wid   = t >> 6;
    const int fr    = lane & 15;
    const int fq    = lane >> 4;
    const int q0    = blockIdx.x * 64;
    const int h     = blockIdx.y;
    const int split = blockIdx.z;
    const int ktbase = split * 16;            // 16 tiles of 64 keys each

    const int srow = t >> 3;
    const int soff = 8 * ((t & 7) ^ (srow & 7));

    const int fr7_16 = (fr & 7) << 4;
    const int rb0 = ((fq * 16) ^ fr7_16) >> 1;
    const int rb1 = ((64 + fq * 16) ^ fr7_16) >> 1;

    bf16x8 qF[2];
#pragma unroll
    for (int kc = 0; kc < 2; ++kc)
        qF[kc] = ldfrag(&qkv[(size_t)(q0 + wid * 16 + fr) * 3072 + h * 64 + kc * 32 + fq * 8]);

    auto stage = [&](int kt_, int b_) {
#pragma unroll
        for (int s2 = 0; s2 < 2; ++s2) {
            glds16(qkv + (size_t)(kt_ * 64 + srow + 32 * s2) * 3072 + 1024 + h * 64 + soff,
                   &Klds[b_][wid * 512 + s2 * 2048]);
            glds16(vt + (size_t)(h * 64 + srow + 32 * s2) * 2048 + kt_ * 64 + soff,
                   &Vlds[b_][wid * 512 + s2 * 2048]);
        }
    };

    float lrun = 0.f;
    f32x4 oacc[4];
#pragma unroll
    for (int n = 0; n < 4; ++n) oacc[n] = (f32x4){0.f, 0.f, 0.f, 0.f};

    stage(ktbase, 0);
    __syncthreads();

    for (int kt = 0; kt < 16; ++kt) {
        const int cb = kt & 1;
        if (kt < 15) stage(ktbase + kt + 1, cb ^ 1);

        // ---- S^T = K @ Q^T (log2 units) ----
        f32x4 sacc[4];
        __builtin_amdgcn_s_setprio(1);
#pragma unroll
        for (int m = 0; m < 4; ++m) {
            const bf16x8 a0 = ldfrag(&Klds[cb][(m * 16 + fr) * 64 + rb0]);
            const bf16x8 a1 = ldfrag(&Klds[cb][(m * 16 + fr) * 64 + rb1]);
            sacc[m] = __builtin_amdgcn_mfma_f32_16x16x32_bf16(a0, qF[0],
                          (f32x4){0.f, 0.f, 0.f, 0.f}, 0, 0, 0);
            sacc[m] = __builtin_amdgcn_mfma_f32_16x16x32_bf16(a1, qF[1],
                          sacc[m], 0, 0, 0);
        }
        __builtin_amdgcn_s_setprio(0);

        // ---- fixed-shift softmax: P = exp2(S) ----
        float ps = 0.f;
#pragma unroll
        for (int m = 0; m < 4; ++m) {
            bf16x4 pk;
            const float p0 = exp2f(sacc[m][0]); ps += p0; pk[0] = (__bf16)p0;
            const float p1 = exp2f(sacc[m][1]); ps += p1; pk[1] = (__bf16)p1;
            const float p2 = exp2f(sacc[m][2]); ps += p2; pk[2] = (__bf16)p2;
            const float p3 = exp2f(sacc[m][3]); ps += p3; pk[3] = (__bf16)p3;
            *(ushort4*)&Plds[wid][fr * 64 + (((m * 32 + fq * 8) ^ fr7_16) >> 1)] =
                __builtin_bit_cast(ushort4, pk);
        }
        ps += __shfl_xor(ps, 16);
        ps += __shfl_xor(ps, 32);
        lrun += ps;

        // ---- O += P @ Vt^T ----
        const bf16x8 pa0 = ldfrag(&Plds[wid][fr * 64 + rb0]);
        const bf16x8 pa1 = ldfrag(&Plds[wid][fr * 64 + rb1]);
        __builtin_amdgcn_s_setprio(1);
#pragma unroll
        for (int n = 0; n < 4; ++n) {
            const bf16x8 v0 = ldfrag(&Vlds[cb][(n * 16 + fr) * 64 + rb0]);
            const bf16x8 v1 = ldfrag(&Vlds[cb][(n * 16 + fr) * 64 + rb1]);
            oacc[n] = __builtin_amdgcn_mfma_f32_16x16x32_bf16(pa0, v0, oacc[n], 0, 0, 0);
            oacc[n] = __builtin_amdgcn_mfma_f32_16x16x32_bf16(pa1, v1, oacc[n], 0, 0, 0);
        }
        __builtin_amdgcn_s_setprio(0);

        __syncthreads();   // staged next tile complete; all waves done with cb
    }

    // ---- write unnormalized partial O + l ----
    unsigned short* po = partialO + (size_t)split * 2048 * 1024;
#pragma unroll
    for (int n = 0; n < 4; ++n) {
        const size_t base = (size_t)(q0 + wid * 16 + fq * 4) * 1024 + h * 64 + n * 16 + fr;
        po[base]        = f2bf(oacc[n][0]);
        po[base + 1024] = f2bf(oacc[n][1]);
        po[base + 2048] = f2bf(oacc[n][2]);
        po[base + 3072] = f2bf(oacc[n][3]);
    }
    if (fq == 0)
        lsum[(split * 16 + h) * 2048 + q0 + wid * 16 + fr] = lrun;
}

// ---------------------------------------------------------------------------
// y[s][c] = (O0[s][c] + O1[s][c]) / (l0[h][s] + l1[h][s]),  h = c>>6
// ---------------------------------------------------------------------------
__global__ __launch_bounds__(256) void merge_attn(
    const unsigned short* __restrict__ partialO, const float* __restrict__ lsum,
    unsigned short* __restrict__ y)
{
    const int idx = blockIdx.x * 256 + threadIdx.x;   // 0..262143, 8 elems each
    const int s  = idx >> 7;
    const int cg = idx & 127;
    const int h  = cg >> 3;
    const float rinv = 1.f / (lsum[h * 2048 + s] + lsum[32768 + h * 2048 + s]);

    union U8 { int4 v; unsigned short u[8]; };
    U8 a, b, o;
    a.v = *(const int4*)&partialO[(size_t)idx * 8];
    b.v = *(const int4*)&partialO[(size_t)idx * 8 + 2097152];
#pragma unroll
    for (int i = 0; i < 8; ++i)
        o.u[i] = f2bf((bf2f(a.u[i]) + bf2f(b.u[i])) * rinv);
    *(int4*)&y[(size_t)idx * 8] = o.v;
}

// ---------------------------------------------------------------------------
extern "C" void kernel_launch(void* const* d_in, const int* in_sizes, int n_in,
                              void* d_out, int out_size, void* d_ws, size_t ws_size,
                              hipStream_t stream)
{
    const float* x       = (const float*)d_in[0];
    const float* W_qkv   = (const float*)d_in[1];
    const float* b_qkv   = (const float*)d_in[2];
    const float* rotary  = (const float*)d_in[3];
    const float* W_dense = (const float*)d_in[4];
    const float* b_dense = (const float*)d_in[5];
    float* out = (float*)d_out;

    char* w = (char*)d_ws;
    unsigned short* w_all   = (unsigned short*)(w);              //  6,291,456 B
    unsigned short* qkv_bf  = (unsigned short*)(w + 6291456);    // 12,582,912
    unsigned short* y_bf    = (unsigned short*)(w + 18874368);   //  4,194,304
    unsigned short* x_bf    = (unsigned short*)(w + 23068672);   //  4,194,304
    unsigned short* rot_t   = (unsigned short*)(w + 27262976);   //  2,097,152
    unsigned short* wq_t    = (unsigned short*)(w + 29360128);   //  2,097,152
    unsigned short* wd_bf   = (unsigned short*)(w + 31457280);   //  2,097,152
    unsigned short* vt      = (unsigned short*)(w + 33554432);   //  4,194,304
    float*          b_all   = (float*)(w + 37748736);            //     12,288
    float*          lsum    = (float*)(w + 37761024);            //    262,144
    // partial O [2][2048][1024] bf16 = 8,388,608 B aliases x_bf..wq_t
    // (dead after qkv-gemm / G-gemm)
    unsigned short* partial = (unsigned short*)(w + 23068672);

    fused_cast<<<5632, 256, 0, stream>>>(x, W_qkv, W_dense, rotary,
                                         x_bf, w_all, wd_bf, rot_t, wq_t);
    brot_kernel<<<264, 256, 0, stream>>>(rot_t, b_qkv, b_all);

    // G = R^T Wq -> w_all rows 0..1023
    gemm_bf16mfma<64, 64, 2, 2, true, false, 0><<<dim3(16, 16), 256, 0, stream>>>(
        rot_t, 1024, wq_t, 1024, nullptr, w_all, 1024, 1024);

    // qkv = x @ w_all^T + b_all ; cols<1024 (rotated q) scaled by 0.125*log2e
    gemm_bf16mfma<64, 128, 2, 2, true, true, 1><<<dim3(24, 32), 256, 0, stream>>>(
        x_bf, 1024, w_all, 1024, b_all, qkv_bf, 3072, 1024);

    transpose_v<<<dim3(32, 16), 256, 0, stream>>>(qkv_bf, vt);

    // attention: 32 q-tiles x 16 heads x 2 KV-splits
    attn_mfma<<<dim3(32, 16, 2), 256, 0, stream>>>(qkv_bf, vt, partial, lsum);
    merge_attn<<<1024, 256, 0, stream>>>(partial, lsum, y_bf);

    gemm_bf16mfma<64, 64, 2, 2, false, true, 0><<<dim3(16, 32), 256, 0, stream>>>(
        y_bf, 1024, wd_bf, 1024, b_dense, out, 1024, 1024);
}

// Round 7
// 109.151 us; speedup vs baseline: 6.4524x; 1.0221x over previous
//
#include <hip/hip_runtime.h>
#include <math.h>

// B=1, S=2048, E=1024, nh=16, hs=64.
// Pipeline:
//   fused_cast: x->bf16; W_qkv[1024:3072]->w_all kv part; W_dense->bf16;
//               rotary^T->rot_t; W_qkv[0:1024]^T->wq_t
//   brot:       b_all[0:1024] = R^T b_q ; rest copied
//   G-gemm:     w_all[0:1024] = rot_t @ wq_t^T  (= R^T Wq, folded rotary)
//   qkv-gemm:   qkv_bf = x @ w_all^T + b_all; cols<1024 scaled 0.125*log2e
//   transpose_v, attn (8-wave blocks, 128 q-rows, KV-split 2, fixed-shift
//   softmax), merge, dense gemm.

typedef float  f32x4  __attribute__((ext_vector_type(4)));
typedef __bf16 bf16x8 __attribute__((ext_vector_type(8)));
typedef __bf16 bf16x4 __attribute__((ext_vector_type(4)));

__device__ __forceinline__ unsigned short f2bf(float f) {
    unsigned int u = __builtin_bit_cast(unsigned int, f);
    u += 0x7FFFu + ((u >> 16) & 1u);            // RNE
    return (unsigned short)(u >> 16);
}
__device__ __forceinline__ float bf2f(unsigned short h) {
    return __builtin_bit_cast(float, (unsigned int)h << 16);
}
__device__ __forceinline__ void glds16(const unsigned short* g, unsigned short* l) {
    __builtin_amdgcn_global_load_lds(
        (const __attribute__((address_space(1))) void*)g,
        (__attribute__((address_space(3))) void*)l, 16, 0, 0);
}
__device__ __forceinline__ bf16x8 ldfrag(const unsigned short* p) {
    return __builtin_bit_cast(bf16x8, *(const int4*)p);
}

// ---------------------------------------------------------------------------
// bf16 MFMA GEMM, NT: C[M,N] = A[M,K] * B[N,K]^T (+bias).
// SCALE_MODE 1: multiply cols<1024 by 0.125*log2(e) after bias.
// ---------------------------------------------------------------------------
template <int BM, int BN, int WGM, int WGN, bool OUT_BF16, bool HAS_BIAS, int SCALE_MODE>
__global__ __launch_bounds__(256) void gemm_bf16mfma(
    const unsigned short* __restrict__ A, int lda,
    const unsigned short* __restrict__ B, int ldb,
    const float* __restrict__ bias,
    void* __restrict__ Cv, int ldc, int K)
{
    constexpr int WM = BM / WGM, WN = BN / WGN;
    constexpr int FM = WM / 16, FN = WN / 16;
    __shared__ unsigned short As[BM * 32];
    __shared__ unsigned short Bs[BN * 32];

    const int t    = threadIdx.x;
    const int lane = t & 63;
    const int wid  = t >> 6;
    const int wr   = wid / WGN;
    const int wc   = wid % WGN;
    const int bm   = blockIdx.y * BM;
    const int bn   = blockIdx.x * BN;

    const int srow = t >> 2;
    const int scol = (t & 3) * 8;
    unsigned short* ldsA = As + (t & 192) * 8;
    unsigned short* ldsB = Bs + (t & 192) * 8;

    const int fr = lane & 15;
    const int fq = lane >> 4;

    f32x4 acc[FM][FN];
#pragma unroll
    for (int i = 0; i < FM; ++i)
#pragma unroll
        for (int j = 0; j < FN; ++j) acc[i][j] = (f32x4){0.f, 0.f, 0.f, 0.f};

    const size_t a_base = (size_t)(bm + srow) * lda + scol;
    const size_t b_base = (size_t)(bn + srow) * ldb + scol;

    for (int k0 = 0; k0 < K; k0 += 32) {
#pragma unroll
        for (int p = 0; p < BM / 64; ++p)
            glds16(A + a_base + (size_t)p * 64 * lda + k0, ldsA + p * 2048);
#pragma unroll
        for (int p = 0; p < BN / 64; ++p)
            glds16(B + b_base + (size_t)p * 64 * ldb + k0, ldsB + p * 2048);
        __syncthreads();

        bf16x8 aF[FM], bF[FN];
#pragma unroll
        for (int m = 0; m < FM; ++m)
            aF[m] = ldfrag(As + (wr * WM + m * 16 + fr) * 32 + fq * 8);
#pragma unroll
        for (int n = 0; n < FN; ++n)
            bF[n] = ldfrag(Bs + (wc * WN + n * 16 + fr) * 32 + fq * 8);
#pragma unroll
        for (int m = 0; m < FM; ++m)
#pragma unroll
            for (int n = 0; n < FN; ++n)
                acc[m][n] = __builtin_amdgcn_mfma_f32_16x16x32_bf16(
                    aF[m], bF[n], acc[m][n], 0, 0, 0);
        __syncthreads();
    }

#pragma unroll
    for (int m = 0; m < FM; ++m) {
        const int row0 = bm + wr * WM + m * 16 + fq * 4;
#pragma unroll
        for (int n = 0; n < FN; ++n) {
            const int col = bn + wc * WN + n * 16 + fr;
            const float bv = HAS_BIAS ? bias[col] : 0.f;
#pragma unroll
            for (int j = 0; j < 4; ++j) {
                float v = acc[m][n][j] + bv;
                if (SCALE_MODE == 1 && col < 1024)
                    v *= 0.18033688011112042f;  // 0.125 * log2(e)
                if (OUT_BF16)
                    ((unsigned short*)Cv)[(size_t)(row0 + j) * ldc + col] = f2bf(v);
                else
                    ((float*)Cv)[(size_t)(row0 + j) * ldc + col] = v;
            }
        }
    }
}

// ---------------------------------------------------------------------------
// Fused casts / transposes.
// ---------------------------------------------------------------------------
__global__ __launch_bounds__(256) void fused_cast(
    const float* __restrict__ x, const float* __restrict__ Wq,
    const float* __restrict__ Wd, const float* __restrict__ rot,
    unsigned short* __restrict__ x_bf, unsigned short* __restrict__ w_all,
    unsigned short* __restrict__ wd_bf, unsigned short* __restrict__ rot_t,
    unsigned short* __restrict__ wq_t)
{
    __shared__ unsigned short tile[64][68];
    const int b = blockIdx.x;
    const int t = threadIdx.x;

    if (b < 5120) {
        const float4* in;
        ushort4* out;
        int i;
        if (b < 2048) {
            in = (const float4*)x;               out = (ushort4*)x_bf;
            i = b * 256 + t;
        } else if (b < 4096) {
            in = (const float4*)Wq + 262144;     out = (ushort4*)w_all + 262144;
            i = (b - 2048) * 256 + t;
        } else {
            in = (const float4*)Wd;              out = (ushort4*)wd_bf;
            i = (b - 4096) * 256 + t;
        }
        const float4 v = in[i];
        ushort4 o;
        o.x = f2bf(v.x); o.y = f2bf(v.y); o.z = f2bf(v.z); o.w = f2bf(v.w);
        out[i] = o;
        return;
    }

    const bool is_rot = (b < 5376);
    const float* in          = is_rot ? rot   : Wq;
    unsigned short* out      = is_rot ? rot_t : wq_t;
    const int tb = (b - 5120) & 255;
    const int bn = (tb & 15) * 64;
    const int bk = (tb >> 4) * 64;
    const int tr = t >> 4;
    const int tc = (t & 15) * 4;
#pragma unroll
    for (int p = 0; p < 4; ++p) {
        const int r = tr + p * 16;
        const float4 v = *(const float4*)&in[(size_t)(bk + r) * 1024 + bn + tc];
        tile[tc + 0][r] = f2bf(v.x);
        tile[tc + 1][r] = f2bf(v.y);
        tile[tc + 2][r] = f2bf(v.z);
        tile[tc + 3][r] = f2bf(v.w);
    }
    __syncthreads();
#pragma unroll
    for (int p = 0; p < 4; ++p) {
        const int r = tr + p * 16;
        ushort4 o;
        o.x = tile[r][tc + 0];
        o.y = tile[r][tc + 1];
        o.z = tile[r][tc + 2];
        o.w = tile[r][tc + 3];
        *(ushort4*)&out[(size_t)(bn + r) * 1024 + bk + tc] = o;
    }
}

// ---------------------------------------------------------------------------
__global__ __launch_bounds__(256) void brot_kernel(
    const unsigned short* __restrict__ rot_t, const float* __restrict__ b_qkv,
    float* __restrict__ b_all)
{
    const int b = blockIdx.x;
    const int t = threadIdx.x;
    if (b < 256) {
        const int d = b * 4 + (t >> 6);
        const int l = t & 63;
        float acc = 0.f;
#pragma unroll
        for (int i = 0; i < 16; ++i) {
            const int e = i * 64 + l;
            acc += bf2f(rot_t[(size_t)d * 1024 + e]) * b_qkv[e];
        }
#pragma unroll
        for (int off = 1; off < 64; off <<= 1) acc += __shfl_xor(acc, off);
        if (l == 0) b_all[d] = acc;
    } else {
        const int idx = 1024 + (b - 256) * 256 + t;
        b_all[idx] = b_qkv[idx];
    }
}

// ---------------------------------------------------------------------------
__global__ __launch_bounds__(256) void transpose_v(
    const unsigned short* __restrict__ qkv, unsigned short* __restrict__ vt)
{
    __shared__ unsigned short tile[64][65];
    const int bs = blockIdx.x * 64;
    const int bc = blockIdx.y * 64;
    const int t  = threadIdx.x;

    union U8 { int4 v; unsigned short u[8]; };
#pragma unroll
    for (int p = 0; p < 2; ++p) {
        const int s = (t >> 3) + p * 32;
        const int c = (t & 7) * 8;
        U8 ld;
        ld.v = *(const int4*)&qkv[(size_t)(bs + s) * 3072 + 2048 + bc + c];
#pragma unroll
        for (int i = 0; i < 8; ++i) tile[s][c + i] = ld.u[i];
    }
    __syncthreads();
#pragma unroll
    for (int p = 0; p < 2; ++p) {
        const int r  = (t >> 3) + p * 32;
        const int sc = (t & 7) * 8;
        U8 st;
#pragma unroll
        for (int i = 0; i < 8; ++i) st.u[i] = tile[sc + i][r];
        *(int4*)&vt[(size_t)(bc + r) * 2048 + bs + sc] = st.v;
    }
}

// ---------------------------------------------------------------------------
// MFMA flash attention: 8 waves x 16 q-rows = 128 q-rows/block, KVBLK=64,
// KV-split 2-way. Fixed-shift softmax (P = exp2(S)), unnormalized partials.
// LDS 48KB -> 2 blocks/CU, 16 waves/CU.
// ---------------------------------------------------------------------------
__global__ __launch_bounds__(512) void attn_mfma(
    const unsigned short* __restrict__ qkv,   // [2048][3072] (q pre-scaled)
    const unsigned short* __restrict__ vt,    // [1024][2048]
    unsigned short* __restrict__ partialO,    // [2][2048][1024] bf16
    float* __restrict__ lsum)                 // [2][16][2048]
{
    __shared__ unsigned short Klds[2][4096];  // [key][d] swizzled
    __shared__ unsigned short Vlds[2][4096];  // [d][key] swizzled
    __shared__ unsigned short Plds[8][1024];  // per-wave [q][key] swizzled

    const int t     = threadIdx.x;
    const int lane  = t & 63;
    const int wid   = t >> 6;                 // 0..7
    const int fr    = lane & 15;
    const int fq    = lane >> 4;
    const int q0    = blockIdx.x * 128;
    const int h     = blockIdx.y;
    const int split = blockIdx.z;
    const int ktbase = split * 16;            // 16 tiles of 64 keys

    // staging: 512 threads x 16B = one full 64x64 bf16 tile per glds call
    const int srow = t >> 3;                      // 0..63
    const int soff = 8 * ((t & 7) ^ (srow & 7));  // pre-swizzled source col
    unsigned short* const kdst = (unsigned short*)Klds[0] + wid * 512;
    unsigned short* const vdst = (unsigned short*)Vlds[0] + wid * 512;

    const int fr7_16 = (fr & 7) << 4;
    const int rb0 = ((fq * 16) ^ fr7_16) >> 1;
    const int rb1 = ((64 + fq * 16) ^ fr7_16) >> 1;

    bf16x8 qF[2];
#pragma unroll
    for (int kc = 0; kc < 2; ++kc)
        qF[kc] = ldfrag(&qkv[(size_t)(q0 + wid * 16 + fr) * 3072 + h * 64 + kc * 32 + fq * 8]);

    auto stage = [&](int kt_, int b_) {
        glds16(qkv + (size_t)(kt_ * 64 + srow) * 3072 + 1024 + h * 64 + soff,
               kdst + b_ * 4096);
        glds16(vt + (size_t)(h * 64 + srow) * 2048 + kt_ * 64 + soff,
               vdst + b_ * 4096);
    };

    float lrun = 0.f;
    f32x4 oacc[4];
#pragma unroll
    for (int n = 0; n < 4; ++n) oacc[n] = (f32x4){0.f, 0.f, 0.f, 0.f};

    stage(ktbase, 0);
    __syncthreads();

    for (int kt = 0; kt < 16; ++kt) {
        const int cb = kt & 1;
        if (kt < 15) stage(ktbase + kt + 1, cb ^ 1);

        // ---- S^T = K @ Q^T (log2 units) ----
        f32x4 sacc[4];
        __builtin_amdgcn_s_setprio(1);
#pragma unroll
        for (int m = 0; m < 4; ++m) {
            const bf16x8 a0 = ldfrag(&Klds[cb][(m * 16 + fr) * 64 + rb0]);
            const bf16x8 a1 = ldfrag(&Klds[cb][(m * 16 + fr) * 64 + rb1]);
            sacc[m] = __builtin_amdgcn_mfma_f32_16x16x32_bf16(a0, qF[0],
                          (f32x4){0.f, 0.f, 0.f, 0.f}, 0, 0, 0);
            sacc[m] = __builtin_amdgcn_mfma_f32_16x16x32_bf16(a1, qF[1],
                          sacc[m], 0, 0, 0);
        }
        __builtin_amdgcn_s_setprio(0);

        // ---- fixed-shift softmax: P = exp2(S) ----
        float ps = 0.f;
#pragma unroll
        for (int m = 0; m < 4; ++m) {
            bf16x4 pk;
            const float p0 = exp2f(sacc[m][0]); ps += p0; pk[0] = (__bf16)p0;
            const float p1 = exp2f(sacc[m][1]); ps += p1; pk[1] = (__bf16)p1;
            const float p2 = exp2f(sacc[m][2]); ps += p2; pk[2] = (__bf16)p2;
            const float p3 = exp2f(sacc[m][3]); ps += p3; pk[3] = (__bf16)p3;
            *(ushort4*)&Plds[wid][fr * 64 + (((m * 32 + fq * 8) ^ fr7_16) >> 1)] =
                __builtin_bit_cast(ushort4, pk);
        }
        ps += __shfl_xor(ps, 16);
        ps += __shfl_xor(ps, 32);
        lrun += ps;

        // ---- O += P @ Vt^T ----
        const bf16x8 pa0 = ldfrag(&Plds[wid][fr * 64 + rb0]);
        const bf16x8 pa1 = ldfrag(&Plds[wid][fr * 64 + rb1]);
        __builtin_amdgcn_s_setprio(1);
#pragma unroll
        for (int n = 0; n < 4; ++n) {
            const bf16x8 v0 = ldfrag(&Vlds[cb][(n * 16 + fr) * 64 + rb0]);
            const bf16x8 v1 = ldfrag(&Vlds[cb][(n * 16 + fr) * 64 + rb1]);
            oacc[n] = __builtin_amdgcn_mfma_f32_16x16x32_bf16(pa0, v0, oacc[n], 0, 0, 0);
            oacc[n] = __builtin_amdgcn_mfma_f32_16x16x32_bf16(pa1, v1, oacc[n], 0, 0, 0);
        }
        __builtin_amdgcn_s_setprio(0);

        __syncthreads();   // staged next tile complete; all waves done with cb
    }

    // ---- write unnormalized partial O + l ----
    unsigned short* po = partialO + (size_t)split * 2048 * 1024;
#pragma unroll
    for (int n = 0; n < 4; ++n) {
        const size_t base = (size_t)(q0 + wid * 16 + fq * 4) * 1024 + h * 64 + n * 16 + fr;
        po[base]        = f2bf(oacc[n][0]);
        po[base + 1024] = f2bf(oacc[n][1]);
        po[base + 2048] = f2bf(oacc[n][2]);
        po[base + 3072] = f2bf(oacc[n][3]);
    }
    if (fq == 0)
        lsum[(split * 16 + h) * 2048 + q0 + wid * 16 + fr] = lrun;
}

// ---------------------------------------------------------------------------
// y[s][c] = (O0[s][c] + O1[s][c]) / (l0[h][s] + l1[h][s]),  h = c>>6
// ---------------------------------------------------------------------------
__global__ __launch_bounds__(256) void merge_attn(
    const unsigned short* __restrict__ partialO, const float* __restrict__ lsum,
    unsigned short* __restrict__ y)
{
    const int idx = blockIdx.x * 256 + threadIdx.x;
    const int s  = idx >> 7;
    const int cg = idx & 127;
    const int h  = cg >> 3;
    const float rinv = 1.f / (lsum[h * 2048 + s] + lsum[32768 + h * 2048 + s]);

    union U8 { int4 v; unsigned short u[8]; };
    U8 a, b, o;
    a.v = *(const int4*)&partialO[(size_t)idx * 8];
    b.v = *(const int4*)&partialO[(size_t)idx * 8 + 2097152];
#pragma unroll
    for (int i = 0; i < 8; ++i)
        o.u[i] = f2bf((bf2f(a.u[i]) + bf2f(b.u[i])) * rinv);
    *(int4*)&y[(size_t)idx * 8] = o.v;
}

// ---------------------------------------------------------------------------
extern "C" void kernel_launch(void* const* d_in, const int* in_sizes, int n_in,
                              void* d_out, int out_size, void* d_ws, size_t ws_size,
                              hipStream_t stream)
{
    const float* x       = (const float*)d_in[0];
    const float* W_qkv   = (const float*)d_in[1];
    const float* b_qkv   = (const float*)d_in[2];
    const float* rotary  = (const float*)d_in[3];
    const float* W_dense = (const float*)d_in[4];
    const float* b_dense = (const float*)d_in[5];
    float* out = (float*)d_out;

    char* w = (char*)d_ws;
    unsigned short* w_all   = (unsigned short*)(w);              //  6,291,456 B
    unsigned short* qkv_bf  = (unsigned short*)(w + 6291456);    // 12,582,912
    unsigned short* y_bf    = (unsigned short*)(w + 18874368);   //  4,194,304
    unsigned short* x_bf    = (unsigned short*)(w + 23068672);   //  4,194,304
    unsigned short* rot_t   = (unsigned short*)(w + 27262976);   //  2,097,152
    unsigned short* wq_t    = (unsigned short*)(w + 29360128);   //  2,097,152
    unsigned short* wd_bf   = (unsigned short*)(w + 31457280);   //  2,097,152
    unsigned short* vt      = (unsigned short*)(w + 33554432);   //  4,194,304
    float*          b_all   = (float*)(w + 37748736);            //     12,288
    float*          lsum    = (float*)(w + 37761024);            //    262,144
    // partial O [2][2048][1024] bf16 = 8,388,608 B aliases x_bf..wq_t
    unsigned short* partial = (unsigned short*)(w + 23068672);

    fused_cast<<<5632, 256, 0, stream>>>(x, W_qkv, W_dense, rotary,
                                         x_bf, w_all, wd_bf, rot_t, wq_t);
    brot_kernel<<<264, 256, 0, stream>>>(rot_t, b_qkv, b_all);

    // G = R^T Wq -> w_all rows 0..1023
    gemm_bf16mfma<64, 64, 2, 2, true, false, 0><<<dim3(16, 16), 256, 0, stream>>>(
        rot_t, 1024, wq_t, 1024, nullptr, w_all, 1024, 1024);

    // qkv = x @ w_all^T + b_all ; cols<1024 (rotated q) scaled by 0.125*log2e
    gemm_bf16mfma<64, 128, 2, 2, true, true, 1><<<dim3(24, 32), 256, 0, stream>>>(
        x_bf, 1024, w_all, 1024, b_all, qkv_bf, 3072, 1024);

    transpose_v<<<dim3(32, 16), 256, 0, stream>>>(qkv_bf, vt);

    // attention: 16 q-tiles (128 rows) x 16 heads x 2 KV-splits, 512 thr
    attn_mfma<<<dim3(16, 16, 2), 512, 0, stream>>>(qkv_bf, vt, partial, lsum);
    merge_attn<<<1024, 256, 0, stream>>>(partial, lsum, y_bf);

    gemm_bf16mfma<64, 64, 2, 2, false, true, 0><<<dim3(16, 32), 256, 0, stream>>>(
        y_bf, 1024, wd_bf, 1024, b_dense, out, 1024, 1024);
}